// Round 6
// baseline (105.954 us; speedup 1.0000x reference)
//
#include <hip/hip_runtime.h>

#define DI static __device__ __forceinline__

typedef short s16x8 __attribute__((ext_vector_type(8)));
typedef float f32x4 __attribute__((ext_vector_type(4)));
typedef unsigned u32x2 __attribute__((ext_vector_type(2)));

DI unsigned short f2b(float f) {
  union { float f; unsigned u; } v; v.f = f;
  return (unsigned short)((v.u + 0x7FFF + ((v.u >> 16) & 1)) >> 16);  // RNE
}
DI float b2f(unsigned short s) {
  union { unsigned u; float f; } v; v.u = ((unsigned)s) << 16;
  return v.f;
}
DI unsigned cvtpk(float lo, float hi) {
  unsigned r;
  asm("v_cvt_pk_bf16_f32 %0, %1, %2" : "=v"(r) : "v"(lo), "v"(hi));
  return r;
}
DI f32x4 MFMA(s16x8 a, s16x8 b, f32x4 c) {
  return __builtin_amdgcn_mfma_f32_16x16x32_bf16(a, b, c, 0, 0, 0);
}
DI s16x8 ldg8(const unsigned short* p) { return *(const s16x8*)p; }

// ---- ws layout (short offsets) ----
#define OFF_WEN   0        // [2048 winT | 8192 wresT] per stack (W^T, A-operand layout)
#define OFF_WAL   10240
#define OFF_WHOW  20480
#define OFF_WHOB  30720
#define OFF_BGEN  40960    // [21][64][32]
#define OFF_BGAL  83968
#define OFF_WIT   126976   // [192][64]
#define OFF_WHT   139264
#define OFF_FC1T  151552   // [64][32]
#define OFF_FC2E  153600   // [16][64] cols:0-5 fc2, 6 how_bout
#define OFF_HOWT  154624   // [64][64]
#define SH_END    159744
// byte offsets
#define B_EMB_EN  (SH_END*2)
#define B_EMB_AL  (B_EMB_EN + 2621440)
#define B_HB      (B_EMB_AL + 2621440)
#define B_GBF     (B_HB + 40960)

#define PSTR 680
#define HSTR 72   // kfused LDS stride

// ================= kprep (layouts unchanged from R5) =================
__global__ __launch_bounds__(256) void kprep(
    const float* __restrict__ hen_win, const float* __restrict__ hen_wres,
    const float* __restrict__ hal_win, const float* __restrict__ hal_wres,
    const float* __restrict__ how_win, const float* __restrict__ how_wres,
    const float* __restrict__ hob_win, const float* __restrict__ hob_wres,
    const float* __restrict__ hen_wout, const float* __restrict__ hen_bout,
    const float* __restrict__ hal_wout, const float* __restrict__ hal_bout,
    const float* __restrict__ gru_wi, const float* __restrict__ gru_wh,
    const float* __restrict__ fc1_w, const float* __restrict__ fc2_w,
    const float* __restrict__ how_bout, const float* __restrict__ how_wout,
    unsigned short* __restrict__ ws)
{
  const int gid = blockIdx.x * 256 + threadIdx.x;
  const int gsz = gridDim.x * 256;
  for (int i = gid; i < 4 * 10240; i += gsz) {
    int s = i / 10240, idx = i - s * 10240;
    const float* win  = (s == 0) ? hen_win  : (s == 1) ? hal_win  : (s == 2) ? how_win  : hob_win;
    const float* wres = (s == 0) ? hen_wres : (s == 1) ? hal_wres : (s == 2) ? how_wres : hob_wres;
    float v;
    if (idx < 2048) { int n = idx >> 5, k = idx & 31; v = (k < 10) ? win[k*64 + n] : 0.f; }
    else { int r = idx - 2048; int d = r >> 12; int r2 = r & 4095; int n = r2 >> 6, k = r2 & 63;
           v = wres[d*4096 + k*64 + n]; }
    ws[s * 10240 + idx] = f2b(v);
  }
  for (int i = gid; i < 2 * 43008; i += gsz) {
    int s = i / 43008, idx = i - s * 43008;
    const float* wout = s ? hal_wout : hen_wout;
    const float* bout = s ? hal_bout : hen_bout;
    int kl = idx & 31, n = (idx >> 5) & 63, c = idx >> 11;
    int kfg = c * 32 + kl;
    float v = 0.f;
    if (kfg < 640)      { int k = kfg / 10, f = kfg - k * 10; v = wout[k*640 + f*64 + n]; }
    else if (kfg < 650) { v = bout[(kfg - 640)*64 + n]; }
    ws[(s ? OFF_BGAL : OFF_BGEN) + idx] = f2b(v);
  }
  for (int i = gid; i < 2 * 12288; i += gsz) {
    int s = i / 12288, idx = i - s * 12288;
    int n = idx >> 6, k = idx & 63;
    const float* w = s ? gru_wh : gru_wi;
    ws[(s ? OFF_WHT : OFF_WIT) + idx] = f2b(w[k*192 + n]);
  }
  for (int i = gid; i < 2048; i += gsz) { int n = i >> 5, k = i & 31; ws[OFF_FC1T + i] = f2b(fc1_w[k*64 + n]); }
  for (int i = gid; i < 1024; i += gsz) {
    int n = i >> 6, k = i & 63;
    float v = 0.f; if (n < 6) v = fc2_w[k*6 + n]; else if (n == 6) v = how_bout[k];
    ws[OFF_FC2E + i] = f2b(v);
  }
  for (int i = gid; i < 4096; i += gsz) ws[OFF_HOWT + i] = f2b(how_wout[i]);
}

// ================= stack on agent-aligned tiles, h in 4 [16][16] planes per tile
// x_lds: [136][16] (rows = a*16+e, e>=E and f>=10 zero). h2: [8 tiles][4 planes][16 e][16 k].
// Wave wv owns tiles {wv, wv+4}. hval: D-layout regs (col=e=lrow, row=k=mt*16+gq*4+r).
DI void stack_planes(const unsigned short* __restrict__ x_lds,
                     unsigned short* __restrict__ h2,
                     const unsigned short* __restrict__ wg,
                     const float* __restrict__ bin, const float* __restrict__ bres,
                     f32x4 (&hval)[2][4])
{
  const int l = threadIdx.x & 63, wv = threadIdx.x >> 6;
  const int lrow = l & 15, gq = l >> 4, lk8 = gq * 8;
  {  // layer 1 (K=32; W zero for k>=10, x b128 row-overflow for gq>=2 is harmless)
    s16x8 wf[4]; f32x4 bv[4];
#pragma unroll
    for (int mt = 0; mt < 4; mt++) {
      wf[mt] = ldg8(wg + (mt*16 + lrow)*32 + lk8);
      bv[mt] = *(const f32x4*)(bin + mt*16 + gq*4);
    }
#pragma unroll
    for (int tt = 0; tt < 2; tt++) {
      int a = wv + tt*4;
      s16x8 xf = *(const s16x8*)&x_lds[(a*16 + lrow)*16 + lk8];
      unsigned short* hw = h2 + a*1024 + lrow*16 + gq*4;
#pragma unroll
      for (int mt = 0; mt < 4; mt++) {
        f32x4 d = MFMA(wf[mt], xf, f32x4{0.f,0.f,0.f,0.f});
#pragma unroll
        for (int r = 0; r < 4; r++) hval[tt][mt][r] = fmaxf(d[r] + bv[mt][r], 0.f);
        u32x2 pw; pw.x = cvtpk(hval[tt][mt][0], hval[tt][mt][1]);
        pw.y = cvtpk(hval[tt][mt][2], hval[tt][mt][3]);
        *(u32x2*)(hw + mt*256) = pw;
      }
    }
  }
#pragma unroll
  for (int d = 0; d < 2; d++) {  // residual layers (K=64 = 2 k-steps)
    const unsigned short* wt = wg + 2048 + d * 4096;
    s16x8 wf0[4], wf1[4]; f32x4 bv[4];
#pragma unroll
    for (int mt = 0; mt < 4; mt++) {
      wf0[mt] = ldg8(wt + (mt*16 + lrow)*64 + lk8);
      wf1[mt] = ldg8(wt + (mt*16 + lrow)*64 + 32 + lk8);
      bv[mt] = *(const f32x4*)(bres + d*64 + mt*16 + gq*4);
    }
#pragma unroll
    for (int tt = 0; tt < 2; tt++) {
      int a = wv + tt*4;
      const unsigned short* hr = h2 + a*1024;
      s16x8 b0 = *(const s16x8*)&hr[(gq>>1)*256 + lrow*16 + (gq&1)*8];
      s16x8 b1 = *(const s16x8*)&hr[(2 + (gq>>1))*256 + lrow*16 + (gq&1)*8];
      unsigned short* hw = h2 + a*1024 + lrow*16 + gq*4;
#pragma unroll
      for (int mt = 0; mt < 4; mt++) {
        f32x4 acc = MFMA(wf0[mt], b0, f32x4{0.f,0.f,0.f,0.f});
        acc = MFMA(wf1[mt], b1, acc);
#pragma unroll
        for (int r = 0; r < 4; r++)
          hval[tt][mt][r] = fmaxf(acc[r] + bv[mt][r], 0.f) + hval[tt][mt][r];
        u32x2 pw; pw.x = cvtpk(hval[tt][mt][0], hval[tt][mt][1]);
        pw.y = cvtpk(hval[tt][mt][2], hval[tt][mt][3]);
        *(u32x2*)(hw + mt*256) = pw;
      }
    }
  }
}

DI void stage_x(const float* __restrict__ feats, int E, unsigned short* x_lds) {
  for (int idx = threadIdx.x; idx < 136*16; idx += 256) {
    int row = idx >> 4, c = idx & 15;
    int a = row >> 4, e = row & 15;
    float v = (a < 8 && e < E && c < 10) ? feats[(a*E + e)*10 + c] : 0.f;
    x_lds[idx] = f2b(v);
  }
}

// ================= khyp body: stack + MFMA P-build + GEMM -> emb (8 n-rows/block)
template<int E>
DI void hyp_body(const float* __restrict__ feats,
                 const unsigned short* __restrict__ Wg, const unsigned short* __restrict__ Bg,
                 const float* __restrict__ bin, const float* __restrict__ bres,
                 float* __restrict__ emb, char* smem)
{
  unsigned short* x_lds = (unsigned short*)smem;           // [136][16]
  unsigned short* h2    = (unsigned short*)(smem + 4352);  // [8][4][16][16]
  unsigned short* P2    = (unsigned short*)smem;           // [8..16][680] overlay
  const int t = threadIdx.x;
  const int l = t & 63, wv = t >> 6;
  const int lrow = l & 15, gq = l >> 4, lk8 = gq * 8;

  stage_x(feats, E, x_lds);
  __syncthreads();   // barrier 1

  f32x4 hval[2][4];
  stack_planes(x_lds, h2, Wg, bin, bres, hval);
  // wave-local: P-build reads only own tiles — no barrier needed here.

  // ---- P-build: C[f][k] = sum_e x^T[f][e] * h[e][k]  (4 MFMAs per agent)
  // A-frag (x^T): slot s=gq*8+j -> e=s (gq<2), zero for gq>=2. B-frag (h) same slots.
  unsigned pkd[2][4][2];   // packed bf16 P fragments (kept across barrier)
#pragma unroll
  for (int tt = 0; tt < 2; tt++) {
    int a = wv + tt*4;
    s16x8 af;
    if (gq < 2) {
#pragma unroll
      for (int j = 0; j < 8; j++) af[j] = (short)x_lds[(a*16 + gq*8 + j)*16 + lrow];
    } else {
#pragma unroll
      for (int j = 0; j < 8; j++) af[j] = 0;
    }
#pragma unroll
    for (int mt = 0; mt < 4; mt++) {
      s16x8 bf;
      if (gq < 2) {
#pragma unroll
        for (int j = 0; j < 8; j++) bf[j] = (short)h2[a*1024 + mt*256 + (gq*8 + j)*16 + lrow];
      } else {
#pragma unroll
        for (int j = 0; j < 8; j++) bf[j] = 0;
      }
      f32x4 p = MFMA(af, bf, f32x4{0.f,0.f,0.f,0.f});
      pkd[tt][mt][0] = cvtpk(p[0], p[1]);
      pkd[tt][mt][1] = cvtpk(p[2], p[3]);
    }
  }
  __syncthreads();   // barrier 2: all x/h reads done; P2 overlays

  // lane (gq,lrow) holds P[f=gq*4+r][k=mt*16+lrow]; kappa = k*10+f (original order)
#pragma unroll
  for (int tt = 0; tt < 2; tt++) {
    int a = wv + tt*4;
#pragma unroll
    for (int mt = 0; mt < 4; mt++) {
      int base = a*PSTR + (mt*16 + lrow)*10 + gq*4;
      if (gq < 2) {
        *(unsigned*)&P2[base]     = pkd[tt][mt][0];
        *(unsigned*)&P2[base + 2] = pkd[tt][mt][1];
      } else if (gq == 2) {
        *(unsigned*)&P2[base]     = pkd[tt][mt][0];
      }
    }
  }
  if (t < 80) {  // sx[a][f] at kappa 640..649 (f32 from global feats)
    int a = t / 10, fx = t - a*10;
    float s = 0.f;
    for (int e = 0; e < E; e++) s += feats[(a*E + e)*10 + fx];
    P2[a*PSTR + 640 + fx] = f2b(s);
  }
  if (t < 176) { int a = t / 22, c = t - (t/22)*22; P2[a*PSTR + 650 + c] = 0; }
  __syncthreads();   // barrier 3: P2 ready

  // ---- GEMM: wave wv owns 16-col n-tile; M rows 8..15 garbage (finite), discarded
  f32x4 acc0 = {0.f,0.f,0.f,0.f}, acc1 = {0.f,0.f,0.f,0.f};
  const unsigned short* Bw = Bg + (wv*16 + lrow)*32 + lk8;
#pragma unroll
  for (int c = 0; c < 21; c++) {
    s16x8 afx = *(const s16x8*)&P2[lrow*PSTR + c*32 + lk8];
    s16x8 bfx = ldg8(Bw + c*2048);
    if (c & 1) acc1 = MFMA(afx, bfx, acc1); else acc0 = MFMA(afx, bfx, acc0);
  }
  if (gq < 2) {
#pragma unroll
    for (int r = 0; r < 4; r++)
      emb[(gq*4 + r)*64 + wv*16 + lrow] = acc0[r] + acc1[r];
  }
}

__global__ __launch_bounds__(256) void khyp_ea(
    const float* __restrict__ en_feats, const float* __restrict__ al_feats,
    const unsigned short* __restrict__ ws,
    const float* __restrict__ en_bin, const float* __restrict__ en_bres,
    const float* __restrict__ al_bin, const float* __restrict__ al_bres,
    float* __restrict__ emb_en, float* __restrict__ emb_al)
{
  __shared__ __align__(16) char smem[21760];
  if (blockIdx.x < 1280) {
    int blk = blockIdx.x;
    hyp_body<11>(en_feats + (long)blk*880, ws + OFF_WEN, ws + OFF_BGEN,
                 en_bin, en_bres, emb_en + (long)blk*512, smem);
  } else {
    int blk = blockIdx.x - 1280;
    hyp_body<9>(al_feats + (long)blk*720, ws + OFF_WAL, ws + OFF_BGAL,
                al_bin, al_bres, emb_al + (long)blk*512, smem);
  }
}

// ================= kfused (unchanged; 16 n/block, all MFMA) =================
__global__ __launch_bounds__(256) void kfused(
    const float* __restrict__ own, const float* __restrict__ agent_emb,
    const float* __restrict__ action_emb,
    const int* __restrict__ agent_idx, const int* __restrict__ last_action,
    const float* __restrict__ emb_en, const float* __restrict__ emb_al,
    const float* __restrict__ hidden,
    const unsigned short* __restrict__ ws,
    const float* __restrict__ fc1_b, const float* __restrict__ bi,
    const float* __restrict__ bh, const float* __restrict__ fc2_b,
    float* __restrict__ qout, float* __restrict__ hhout,
    unsigned short* __restrict__ g_bf, float* __restrict__ hb)
{
  __shared__ unsigned short own_lds[16*32];
  __shared__ unsigned short x_lds[16*HSTR];
  __shared__ unsigned short hp_lds[16*HSTR];
  __shared__ unsigned short hh_lds[16*HSTR];
  const int t = threadIdx.x;
  const int l = t & 63, wv = t >> 6;
  const int lrow = l & 15, lk8 = (l >> 4) * 8, lr4 = (l >> 4) * 4;
  const int n0 = blockIdx.x * 16;

  const unsigned short* fc1T = ws + OFF_FC1T;
  const unsigned short* wiT  = ws + OFF_WIT;
  const unsigned short* whT  = ws + OFF_WHT;
  const unsigned short* howT = ws + OFF_HOWT;
  const unsigned short* fc2e = ws + OFF_FC2E;

  for (int i = t; i < 512; i += 256) own_lds[i] = f2b(own[n0*32 + i]);
  for (int i = t; i < 1024; i += 256) hp_lds[(i >> 6)*HSTR + (i & 63)] = f2b(hidden[n0*64 + i]);
  __syncthreads();

  const int j = wv * 16 + lrow;
  {
    s16x8 a0 = *(const s16x8*)&own_lds[lrow*32 + lk8];
    s16x8 b0 = ldg8(fc1T + (wv*16 + lrow)*32 + lk8);
    f32x4 c0 = MFMA(a0, b0, f32x4{0.f,0.f,0.f,0.f});
    float fb = fc1_b[j];
#pragma unroll
    for (int r = 0; r < 4; r++) {
      int aa = lr4 + r; int n = n0 + aa;
      int ai = agent_idx[n], la = last_action[n];
      float v = c0[r] + fb + agent_emb[ai*64 + j] + action_emb[la*64 + j]
              + emb_en[n*64 + j] + emb_al[n*64 + j];
      x_lds[aa*HSTR + j] = f2b(fmaxf(v, 0.f));
    }
  }
  __syncthreads();

  {
    s16x8 xa[2], ha[2];
#pragma unroll
    for (int s = 0; s < 2; s++) {
      xa[s] = *(const s16x8*)&x_lds[lrow*HSTR + s*32 + lk8];
      ha[s] = *(const s16x8*)&hp_lds[lrow*HSTR + s*32 + lk8];
    }
    f32x4 gi[3], gh[3];
#pragma unroll
    for (int g3 = 0; g3 < 3; g3++) { gi[g3] = f32x4{0.f,0.f,0.f,0.f}; gh[g3] = f32x4{0.f,0.f,0.f,0.f}; }
#pragma unroll
    for (int g3 = 0; g3 < 3; g3++) {
      int tl = wv + g3 * 4;
#pragma unroll
      for (int s = 0; s < 2; s++) {
        gi[g3] = MFMA(xa[s], ldg8(wiT + (tl*16 + lrow)*64 + s*32 + lk8), gi[g3]);
        gh[g3] = MFMA(ha[s], ldg8(whT + (tl*16 + lrow)*64 + s*32 + lk8), gh[g3]);
      }
    }
    float bir = bi[j], biz = bi[64 + j], bin_ = bi[128 + j];
    float bhr = bh[j], bhz = bh[64 + j], bhn = bh[128 + j];
#pragma unroll
    for (int r = 0; r < 4; r++) {
      int aa = lr4 + r; int n = n0 + aa;
      float rr = 1.f / (1.f + __expf(-(gi[0][r] + bir + gh[0][r] + bhr)));
      float zz = 1.f / (1.f + __expf(-(gi[1][r] + biz + gh[1][r] + bhz)));
      float nn = tanhf(gi[2][r] + bin_ + rr * (gh[2][r] + bhn));
      float hp = hidden[n*64 + j];
      float hhv = (1.f - zz) * nn + zz * hp;
      hhout[n*64 + j] = hhv;
      hh_lds[aa*HSTR + j] = f2b(hhv);
    }
  }
  __syncthreads();

  {
    s16x8 hha[2];
#pragma unroll
    for (int s = 0; s < 2; s++) hha[s] = *(const s16x8*)&hh_lds[lrow*HSTR + s*32 + lk8];
    f32x4 gc = {0.f,0.f,0.f,0.f};
#pragma unroll
    for (int s = 0; s < 2; s++) gc = MFMA(hha[s], ldg8(howT + (wv*16 + lrow)*64 + s*32 + lk8), gc);
#pragma unroll
    for (int r = 0; r < 4; r++) g_bf[(n0 + lr4 + r)*64 + wv*16 + lrow] = f2b(gc[r]);
    if (wv == 0) {
      f32x4 qc = {0.f,0.f,0.f,0.f};
#pragma unroll
      for (int s = 0; s < 2; s++) qc = MFMA(hha[s], ldg8(fc2e + lrow*64 + s*32 + lk8), qc);
#pragma unroll
      for (int r = 0; r < 4; r++) {
        int n = n0 + lr4 + r;
        if (lrow < 6)       qout[n*17 + lrow] = qc[r] + fc2_b[lrow];
        else if (lrow == 6) hb[n] = qc[r];
      }
    }
  }
}

// ================= kattack: 8 n/block; 2 stacks; in-register epilogue dots
__global__ __launch_bounds__(256) void kattack(
    const float* __restrict__ en_feats, const unsigned short* __restrict__ ws,
    const float* __restrict__ how_bin, const float* __restrict__ how_bres,
    const float* __restrict__ hob_bin, const float* __restrict__ hob_bres,
    const unsigned short* __restrict__ g_bf, const float* __restrict__ hbuf,
    const float* __restrict__ hob_wout, const float* __restrict__ hob_bout,
    float* __restrict__ qout)
{
  __shared__ __align__(16) char smem[20736];
  unsigned short* x_lds = (unsigned short*)smem;           // [136][16]
  unsigned short* h2    = (unsigned short*)(smem + 4352);  // [8][4][16][16]
  const int t = threadIdx.x;
  const int l = t & 63, wv = t >> 6;
  const int lrow = l & 15, gq = l >> 4;
  const int blk = blockIdx.x;
  const float* feats = en_feats + (long)blk * 880;

  stage_x(feats, 11, x_lds);
  __syncthreads();   // the only barrier

  f32x4 hval[2][4];

  // ---- hob stack -> qB from registers
  stack_planes(x_lds, h2, ws + OFF_WHOB, hob_bin, hob_bres, hval);
  f32x4 hw[4];
#pragma unroll
  for (int mt = 0; mt < 4; mt++) hw[mt] = *(const f32x4*)(hob_wout + mt*16 + gq*4);
  float qbv[2];
#pragma unroll
  for (int tt = 0; tt < 2; tt++) {
    float s = 0.f;
#pragma unroll
    for (int mt = 0; mt < 4; mt++)
#pragma unroll
      for (int r = 0; r < 4; r++) s += hval[tt][mt][r] * hw[mt][r];
    s += __shfl_xor(s, 16, 64);
    s += __shfl_xor(s, 32, 64);
    qbv[tt] = s;
  }

  // ---- how stack -> q_attack
  stack_planes(x_lds, h2, ws + OFF_WHOW, how_bin, how_bres, hval);
  const float hob_b0 = hob_bout[0];
#pragma unroll
  for (int tt = 0; tt < 2; tt++) {
    int n = blk*8 + wv + tt*4;
    float s = 0.f;
#pragma unroll
    for (int mt = 0; mt < 4; mt++) {
      u32x2 gv = *(const u32x2*)(g_bf + (long)n*64 + mt*16 + gq*4);
      s += hval[tt][mt][0] * b2f((unsigned short)(gv.x & 0xFFFF))
         + hval[tt][mt][1] * b2f((unsigned short)(gv.x >> 16))
         + hval[tt][mt][2] * b2f((unsigned short)(gv.y & 0xFFFF))
         + hval[tt][mt][3] * b2f((unsigned short)(gv.y >> 16));
    }
    s += __shfl_xor(s, 16, 64);
    s += __shfl_xor(s, 32, 64);
    if (gq == 0 && lrow < 11)
      qout[n*17 + 6 + lrow] = s + qbv[tt] + hbuf[n] + hob_b0;
  }
}

extern "C" void kernel_launch(void* const* d_in, const int* in_sizes, int n_in,
                              void* d_out, int out_size, void* d_ws, size_t ws_size,
                              hipStream_t stream)
{
  (void)in_sizes; (void)n_in; (void)out_size; (void)ws_size;
  const float* own        = (const float*)d_in[0];
  const float* enemy      = (const float*)d_in[1];
  const float* ally       = (const float*)d_in[2];
  const float* hidden     = (const float*)d_in[3];
  const float* fc1_w      = (const float*)d_in[4];
  const float* fc1_b      = (const float*)d_in[5];
  const float* agent_emb  = (const float*)d_in[6];
  const float* action_emb = (const float*)d_in[7];
  const float* hen_win  = (const float*)d_in[8];  const float* hen_bin  = (const float*)d_in[9];
  const float* hen_wres = (const float*)d_in[10]; const float* hen_bres = (const float*)d_in[11];
  const float* hen_wout = (const float*)d_in[12]; const float* hen_bout = (const float*)d_in[13];
  const float* hal_win  = (const float*)d_in[14]; const float* hal_bin  = (const float*)d_in[15];
  const float* hal_wres = (const float*)d_in[16]; const float* hal_bres = (const float*)d_in[17];
  const float* hal_wout = (const float*)d_in[18]; const float* hal_bout = (const float*)d_in[19];
  const float* gru_wi = (const float*)d_in[20];   const float* gru_wh = (const float*)d_in[21];
  const float* gru_bi = (const float*)d_in[22];   const float* gru_bh = (const float*)d_in[23];
  const float* fc2_w  = (const float*)d_in[24];   const float* fc2_b  = (const float*)d_in[25];
  const float* how_win  = (const float*)d_in[26]; const float* how_bin  = (const float*)d_in[27];
  const float* how_wres = (const float*)d_in[28]; const float* how_bres = (const float*)d_in[29];
  const float* how_wout = (const float*)d_in[30]; const float* how_bout = (const float*)d_in[31];
  const float* hob_win  = (const float*)d_in[32]; const float* hob_bin  = (const float*)d_in[33];
  const float* hob_wres = (const float*)d_in[34]; const float* hob_bres = (const float*)d_in[35];
  const float* hob_wout = (const float*)d_in[36]; const float* hob_bout = (const float*)d_in[37];
  const int* agent_idx   = (const int*)d_in[38];
  const int* last_action = (const int*)d_in[39];

  unsigned short* ws = (unsigned short*)d_ws;
  float* emb_en = (float*)((char*)d_ws + B_EMB_EN);
  float* emb_al = (float*)((char*)d_ws + B_EMB_AL);
  float* hb     = (float*)((char*)d_ws + B_HB);
  unsigned short* g_bf = (unsigned short*)((char*)d_ws + B_GBF);

  float* q  = (float*)d_out;
  float* hh = q + 1024*10*17;

  kprep<<<128, 256, 0, stream>>>(hen_win, hen_wres, hal_win, hal_wres,
      how_win, how_wres, hob_win, hob_wres,
      hen_wout, hen_bout, hal_wout, hal_bout,
      gru_wi, gru_wh, fc1_w, fc2_w, how_bout, how_wout, ws);
  khyp_ea<<<2560, 256, 0, stream>>>(enemy, ally, ws,
      hen_bin, hen_bres, hal_bin, hal_bres, emb_en, emb_al);
  kfused<<<640, 256, 0, stream>>>(own, agent_emb, action_emb, agent_idx, last_action,
      emb_en, emb_al, hidden, ws, fc1_b, gru_bi, gru_bh, fc2_b, q, hh, g_bf, hb);
  kattack<<<1280, 256, 0, stream>>>(enemy, ws, how_bin, how_bres, hob_bin, hob_bres,
      g_bf, hb, hob_wout, hob_bout, q);
}

// Round 7
// 100.766 us; speedup vs baseline: 1.0515x; 1.0515x over previous
//
#include <hip/hip_runtime.h>

#define DI static __device__ __forceinline__

typedef short s16x8 __attribute__((ext_vector_type(8)));
typedef float f32x4 __attribute__((ext_vector_type(4)));
typedef unsigned u32x2 __attribute__((ext_vector_type(2)));

DI unsigned short f2b(float f) {
  union { float f; unsigned u; } v; v.f = f;
  return (unsigned short)((v.u + 0x7FFF + ((v.u >> 16) & 1)) >> 16);  // RNE
}
DI float b2f(unsigned short s) {
  union { unsigned u; float f; } v; v.u = ((unsigned)s) << 16;
  return v.f;
}
DI unsigned cvtpk(float lo, float hi) {
  unsigned r;
  asm("v_cvt_pk_bf16_f32 %0, %1, %2" : "=v"(r) : "v"(lo), "v"(hi));
  return r;
}
DI f32x4 MFMA(s16x8 a, s16x8 b, f32x4 c) {
  return __builtin_amdgcn_mfma_f32_16x16x32_bf16(a, b, c, 0, 0, 0);
}
DI s16x8 ldg8(const unsigned short* p) { return *(const s16x8*)p; }

// ---- ws layout (short offsets) ----
#define OFF_WEN   0        // [2048 winT | 8192 wresT] per stack (W^T, A-operand layout)
#define OFF_WAL   10240
#define OFF_WHOW  20480
#define OFF_WHOB  30720
#define OFF_BGEN  40960    // [21][64][32]
#define OFF_BGAL  83968
#define OFF_WIT   126976   // [192][64]
#define OFF_WHT   139264
#define OFF_FC1T  151552   // [64][32]
#define OFF_FC2E  153600   // [16][64] cols:0-5 fc2, 6 how_bout
#define OFF_HOWT  154624   // [64][64]
#define SH_END    159744
// byte offsets
#define B_EMB_EN  (SH_END*2)
#define B_EMB_AL  (B_EMB_EN + 2621440)
#define B_HB      (B_EMB_AL + 2621440)
#define B_GBF     (B_HB + 40960)

#define PSTR 680
#define HSTR 72          // kfused LDS stride
#define XB   3072        // x region bytes in hyp/attack smem ([96][16] shorts)
#define SMEMB 15360      // 3072 + 96*128

// swizzled byte offsets (row-XOR on bits 4..6; identical at write & read)
DI int xoff(int row, int byte_in_row) { return ((row*32  + byte_in_row) ^ ((row & 7) << 4)); }
DI int hoff(int row, int byte_in_row) { return XB + ((row*128 + byte_in_row) ^ ((row & 7) << 4)); }

// ================= kprep (unchanged layouts) =================
__global__ __launch_bounds__(256) void kprep(
    const float* __restrict__ hen_win, const float* __restrict__ hen_wres,
    const float* __restrict__ hal_win, const float* __restrict__ hal_wres,
    const float* __restrict__ how_win, const float* __restrict__ how_wres,
    const float* __restrict__ hob_win, const float* __restrict__ hob_wres,
    const float* __restrict__ hen_wout, const float* __restrict__ hen_bout,
    const float* __restrict__ hal_wout, const float* __restrict__ hal_bout,
    const float* __restrict__ gru_wi, const float* __restrict__ gru_wh,
    const float* __restrict__ fc1_w, const float* __restrict__ fc2_w,
    const float* __restrict__ how_bout, const float* __restrict__ how_wout,
    unsigned short* __restrict__ ws)
{
  const int gid = blockIdx.x * 256 + threadIdx.x;
  const int gsz = gridDim.x * 256;
  for (int i = gid; i < 4 * 10240; i += gsz) {
    int s = i / 10240, idx = i - s * 10240;
    const float* win  = (s == 0) ? hen_win  : (s == 1) ? hal_win  : (s == 2) ? how_win  : hob_win;
    const float* wres = (s == 0) ? hen_wres : (s == 1) ? hal_wres : (s == 2) ? how_wres : hob_wres;
    float v;
    if (idx < 2048) { int n = idx >> 5, k = idx & 31; v = (k < 10) ? win[k*64 + n] : 0.f; }
    else { int r = idx - 2048; int d = r >> 12; int r2 = r & 4095; int n = r2 >> 6, k = r2 & 63;
           v = wres[d*4096 + k*64 + n]; }
    ws[s * 10240 + idx] = f2b(v);
  }
  for (int i = gid; i < 2 * 43008; i += gsz) {
    int s = i / 43008, idx = i - s * 43008;
    const float* wout = s ? hal_wout : hen_wout;
    const float* bout = s ? hal_bout : hen_bout;
    int kl = idx & 31, n = (idx >> 5) & 63, c = idx >> 11;
    int kfg = c * 32 + kl;
    float v = 0.f;
    if (kfg < 640)      { int k = kfg / 10, f = kfg - k * 10; v = wout[k*640 + f*64 + n]; }
    else if (kfg < 650) { v = bout[(kfg - 640)*64 + n]; }
    ws[(s ? OFF_BGAL : OFF_BGEN) + idx] = f2b(v);
  }
  for (int i = gid; i < 2 * 12288; i += gsz) {
    int s = i / 12288, idx = i - s * 12288;
    int n = idx >> 6, k = idx & 63;
    const float* w = s ? gru_wh : gru_wi;
    ws[(s ? OFF_WHT : OFF_WIT) + idx] = f2b(w[k*192 + n]);
  }
  for (int i = gid; i < 2048; i += gsz) { int n = i >> 5, k = i & 31; ws[OFF_FC1T + i] = f2b(fc1_w[k*64 + n]); }
  for (int i = gid; i < 1024; i += gsz) {
    int n = i >> 6, k = i & 63;
    float v = 0.f; if (n < 6) v = fc2_w[k*6 + n]; else if (n == 6) v = how_bout[k];
    ws[OFF_FC2E + i] = f2b(v);
  }
  for (int i = gid; i < 4096; i += gsz) ws[OFF_HOWT + i] = f2b(how_wout[i]);
}

// ================= stage x: [96 rows][16] bf16, swizzled; rows >= vrows zero
DI void stage_x8(const float* __restrict__ feats, int vrows, char* smem) {
  for (int idx = threadIdx.x; idx < 96*16; idx += 256) {
    int row = idx >> 4, c = idx & 15;
    float v = (row < vrows && c < 10) ? feats[row*10 + c] : 0.f;
    *(unsigned short*)(smem + xoff(row, c*2)) = f2b(v);
  }
}

// ================= stack over row-tiles; wave owns tiles {wv, wv+4} (guarded).
// Swapped operands: h^T = W^T x^T. Weights A-operand from global ws; x/h B-operand
// from swizzled LDS. hval regs: lane(gq,lrow) holds h[n=mt*16+gq*4+r][row=tile*16+lrow].
DI void stack8(char* smem, int ntiles,
               const unsigned short* __restrict__ wg,
               const float* __restrict__ bin, const float* __restrict__ bres,
               f32x4 (&hval)[2][4])
{
  const int l = threadIdx.x & 63, wv = threadIdx.x >> 6;
  const int lrow = l & 15, gq = l >> 4, lk8 = gq * 8;
  const int tis[2] = {wv, wv + 4};
  {  // layer 1 (K=32; x slots k>=10 garbage but winT cols k>=10 are zero)
    s16x8 wf[4]; f32x4 bv[4];
#pragma unroll
    for (int mt = 0; mt < 4; mt++) {
      wf[mt] = ldg8(wg + (mt*16 + lrow)*32 + lk8);
      bv[mt] = *(const f32x4*)(bin + mt*16 + gq*4);
    }
#pragma unroll
    for (int tt = 0; tt < 2; tt++) {
      if (tis[tt] < ntiles) {
        int row = tis[tt]*16 + lrow;
        s16x8 xf = *(const s16x8*)(smem + xoff(row, gq*16));
#pragma unroll
        for (int mt = 0; mt < 4; mt++) {
          f32x4 d = MFMA(wf[mt], xf, f32x4{0.f,0.f,0.f,0.f});
#pragma unroll
          for (int r = 0; r < 4; r++) hval[tt][mt][r] = fmaxf(d[r] + bv[mt][r], 0.f);
          u32x2 pw; pw.x = cvtpk(hval[tt][mt][0], hval[tt][mt][1]);
          pw.y = cvtpk(hval[tt][mt][2], hval[tt][mt][3]);
          *(u32x2*)(smem + hoff(row, (mt*16 + gq*4)*2)) = pw;
        }
      }
    }
  }
#pragma unroll
  for (int d = 0; d < 2; d++) {  // residual layers (K=64 = 2 k-steps)
    const unsigned short* wt = wg + 2048 + d * 4096;
    s16x8 wf0[4], wf1[4]; f32x4 bv[4];
#pragma unroll
    for (int mt = 0; mt < 4; mt++) {
      wf0[mt] = ldg8(wt + (mt*16 + lrow)*64 + lk8);
      wf1[mt] = ldg8(wt + (mt*16 + lrow)*64 + 32 + lk8);
      bv[mt] = *(const f32x4*)(bres + d*64 + mt*16 + gq*4);
    }
#pragma unroll
    for (int tt = 0; tt < 2; tt++) {
      if (tis[tt] < ntiles) {
        int row = tis[tt]*16 + lrow;
        s16x8 b0 = *(const s16x8*)(smem + hoff(row, gq*16));
        s16x8 b1 = *(const s16x8*)(smem + hoff(row, 64 + gq*16));
#pragma unroll
        for (int mt = 0; mt < 4; mt++) {
          f32x4 acc = MFMA(wf0[mt], b0, f32x4{0.f,0.f,0.f,0.f});
          acc = MFMA(wf1[mt], b1, acc);
#pragma unroll
          for (int r = 0; r < 4; r++)
            hval[tt][mt][r] = fmaxf(acc[r] + bv[mt][r], 0.f) + hval[tt][mt][r];
          u32x2 pw; pw.x = cvtpk(hval[tt][mt][0], hval[tt][mt][1]);
          pw.y = cvtpk(hval[tt][mt][2], hval[tt][mt][3]);
          *(u32x2*)(smem + hoff(row, (mt*16 + gq*4)*2)) = pw;
        }
      }
    }
  }
}

// ================= khyp body: 8 agents/block =================
template<int E>
DI void hyp_body8(const float* __restrict__ feats,
                  const unsigned short* __restrict__ Wg, const unsigned short* __restrict__ Bg,
                  const float* __restrict__ bin, const float* __restrict__ bres,
                  float* __restrict__ emb, char* smem)
{
  const int t = threadIdx.x;
  const int l = t & 63, wv = t >> 6;
  const int lrow = l & 15, gq = l >> 4, lk8 = gq * 8, lr4 = gq * 4;
  const int rows = 8 * E, ntiles = (rows + 15) >> 4;

  stage_x8(feats, rows, smem);
  __syncthreads();   // bar 1

  f32x4 hval[2][4];
  stack8(smem, ntiles, Wg, bin, bres, hval);
  __syncthreads();   // bar 2: h complete (P-build reads cross-wave rows)

  // ---- P-build: thread = (agent a = t>>5, k pair k2)
  const int a = t >> 5, k2 = (t & 31) * 2;
  float p0[10], p1[10];
#pragma unroll
  for (int f = 0; f < 10; f++) { p0[f] = 0.f; p1[f] = 0.f; }
#pragma unroll
  for (int e = 0; e < E; e++) {
    int row = a * E + e;
    s16x8 xv8 = *(const s16x8*)(smem + xoff(row, 0));
    unsigned xv2 = *(const unsigned*)(smem + xoff(row, 16));
    float xf[10];
#pragma unroll
    for (int f = 0; f < 8; f++) xf[f] = b2f((unsigned short)xv8[f]);
    xf[8] = b2f((unsigned short)(xv2 & 0xFFFF));
    xf[9] = b2f((unsigned short)(xv2 >> 16));
    unsigned hp = *(const unsigned*)(smem + hoff(row, k2*2));
    float h0 = b2f((unsigned short)(hp & 0xFFFF));
    float h1 = b2f((unsigned short)(hp >> 16));
#pragma unroll
    for (int f = 0; f < 10; f++) { p0[f] += h0 * xf[f]; p1[f] += h1 * xf[f]; }
  }
  float sxv = 0.f; int a2 = 0, fx = 0;
  if (t < 80) {
    a2 = t / 10; fx = t - a2 * 10;
    for (int e = 0; e < E; e++) sxv += feats[(a2*E + e)*10 + fx];
  }
  __syncthreads();   // bar 3: all x/h reads done; P2 overlays

  unsigned short* P2 = (unsigned short*)smem;
  unsigned* Pw = (unsigned*)(P2 + a*PSTR + k2*10);
#pragma unroll
  for (int j = 0; j < 5; j++) Pw[j]     = cvtpk(p0[2*j], p0[2*j+1]);
#pragma unroll
  for (int j = 0; j < 5; j++) Pw[5 + j] = cvtpk(p1[2*j], p1[2*j+1]);
  if (t < 80) P2[a2*PSTR + 640 + fx] = f2b(sxv);
  if (t < 176) { int a3 = t / 22, c = t - a3*22; P2[a3*PSTR + 650 + c] = 0; }
  __syncthreads();   // bar 4: P2 ready

  // ---- GEMM: wave wv owns 16-col n-tile; M rows 8..15 duplicate agents (discarded)
  const int arow = lrow & 7;
  f32x4 acc0 = {0.f,0.f,0.f,0.f}, acc1 = {0.f,0.f,0.f,0.f};
  const unsigned short* Bw = Bg + (wv*16 + lrow)*32 + lk8;
#pragma unroll
  for (int c = 0; c < 21; c++) {
    s16x8 af = *(const s16x8*)&P2[arow*PSTR + c*32 + lk8];
    s16x8 bf = ldg8(Bw + c*2048);
    if (c & 1) acc1 = MFMA(af, bf, acc1); else acc0 = MFMA(af, bf, acc0);
  }
  if (l < 32) {
#pragma unroll
    for (int r = 0; r < 4; r++)
      emb[(lr4 + r)*64 + wv*16 + lrow] = acc0[r] + acc1[r];
  }
}

__global__ __launch_bounds__(256) void khyp_ea(
    const float* __restrict__ en_feats, const float* __restrict__ al_feats,
    const unsigned short* __restrict__ ws,
    const float* __restrict__ en_bin, const float* __restrict__ en_bres,
    const float* __restrict__ al_bin, const float* __restrict__ al_bres,
    float* __restrict__ emb_en, float* __restrict__ emb_al)
{
  __shared__ __align__(16) char smem[SMEMB];
  if (blockIdx.x < 1280) {
    int blk = blockIdx.x;
    hyp_body8<11>(en_feats + (long)blk*880, ws + OFF_WEN, ws + OFF_BGEN,
                  en_bin, en_bres, emb_en + (long)blk*512, smem);
  } else {
    int blk = blockIdx.x - 1280;
    hyp_body8<9>(al_feats + (long)blk*720, ws + OFF_WAL, ws + OFF_BGAL,
                 al_bin, al_bres, emb_al + (long)blk*512, smem);
  }
}

// ================= kfused (unchanged; 16 n/block, all MFMA) =================
__global__ __launch_bounds__(256) void kfused(
    const float* __restrict__ own, const float* __restrict__ agent_emb,
    const float* __restrict__ action_emb,
    const int* __restrict__ agent_idx, const int* __restrict__ last_action,
    const float* __restrict__ emb_en, const float* __restrict__ emb_al,
    const float* __restrict__ hidden,
    const unsigned short* __restrict__ ws,
    const float* __restrict__ fc1_b, const float* __restrict__ bi,
    const float* __restrict__ bh, const float* __restrict__ fc2_b,
    float* __restrict__ qout, float* __restrict__ hhout,
    unsigned short* __restrict__ g_bf, float* __restrict__ hb)
{
  __shared__ unsigned short own_lds[16*32];
  __shared__ unsigned short x_lds[16*HSTR];
  __shared__ unsigned short hp_lds[16*HSTR];
  __shared__ unsigned short hh_lds[16*HSTR];
  const int t = threadIdx.x;
  const int l = t & 63, wv = t >> 6;
  const int lrow = l & 15, lk8 = (l >> 4) * 8, lr4 = (l >> 4) * 4;
  const int n0 = blockIdx.x * 16;

  const unsigned short* fc1T = ws + OFF_FC1T;
  const unsigned short* wiT  = ws + OFF_WIT;
  const unsigned short* whT  = ws + OFF_WHT;
  const unsigned short* howT = ws + OFF_HOWT;
  const unsigned short* fc2e = ws + OFF_FC2E;

  for (int i = t; i < 512; i += 256) own_lds[i] = f2b(own[n0*32 + i]);
  for (int i = t; i < 1024; i += 256) hp_lds[(i >> 6)*HSTR + (i & 63)] = f2b(hidden[n0*64 + i]);
  __syncthreads();

  const int j = wv * 16 + lrow;
  {
    s16x8 a0 = *(const s16x8*)&own_lds[lrow*32 + lk8];
    s16x8 b0 = ldg8(fc1T + (wv*16 + lrow)*32 + lk8);
    f32x4 c0 = MFMA(a0, b0, f32x4{0.f,0.f,0.f,0.f});
    float fb = fc1_b[j];
#pragma unroll
    for (int r = 0; r < 4; r++) {
      int aa = lr4 + r; int n = n0 + aa;
      int ai = agent_idx[n], la = last_action[n];
      float v = c0[r] + fb + agent_emb[ai*64 + j] + action_emb[la*64 + j]
              + emb_en[n*64 + j] + emb_al[n*64 + j];
      x_lds[aa*HSTR + j] = f2b(fmaxf(v, 0.f));
    }
  }
  __syncthreads();

  {
    s16x8 xa[2], ha[2];
#pragma unroll
    for (int s = 0; s < 2; s++) {
      xa[s] = *(const s16x8*)&x_lds[lrow*HSTR + s*32 + lk8];
      ha[s] = *(const s16x8*)&hp_lds[lrow*HSTR + s*32 + lk8];
    }
    f32x4 gi[3], gh[3];
#pragma unroll
    for (int g3 = 0; g3 < 3; g3++) { gi[g3] = f32x4{0.f,0.f,0.f,0.f}; gh[g3] = f32x4{0.f,0.f,0.f,0.f}; }
#pragma unroll
    for (int g3 = 0; g3 < 3; g3++) {
      int tl = wv + g3 * 4;
#pragma unroll
      for (int s = 0; s < 2; s++) {
        gi[g3] = MFMA(xa[s], ldg8(wiT + (tl*16 + lrow)*64 + s*32 + lk8), gi[g3]);
        gh[g3] = MFMA(ha[s], ldg8(whT + (tl*16 + lrow)*64 + s*32 + lk8), gh[g3]);
      }
    }
    float bir = bi[j], biz = bi[64 + j], bin_ = bi[128 + j];
    float bhr = bh[j], bhz = bh[64 + j], bhn = bh[128 + j];
#pragma unroll
    for (int r = 0; r < 4; r++) {
      int aa = lr4 + r; int n = n0 + aa;
      float rr = 1.f / (1.f + __expf(-(gi[0][r] + bir + gh[0][r] + bhr)));
      float zz = 1.f / (1.f + __expf(-(gi[1][r] + biz + gh[1][r] + bhz)));
      float nn = tanhf(gi[2][r] + bin_ + rr * (gh[2][r] + bhn));
      float hp = hidden[n*64 + j];
      float hhv = (1.f - zz) * nn + zz * hp;
      hhout[n*64 + j] = hhv;
      hh_lds[aa*HSTR + j] = f2b(hhv);
    }
  }
  __syncthreads();

  {
    s16x8 hha[2];
#pragma unroll
    for (int s = 0; s < 2; s++) hha[s] = *(const s16x8*)&hh_lds[lrow*HSTR + s*32 + lk8];
    f32x4 gc = {0.f,0.f,0.f,0.f};
#pragma unroll
    for (int s = 0; s < 2; s++) gc = MFMA(hha[s], ldg8(howT + (wv*16 + lrow)*64 + s*32 + lk8), gc);
#pragma unroll
    for (int r = 0; r < 4; r++) g_bf[(n0 + lr4 + r)*64 + wv*16 + lrow] = f2b(gc[r]);
    if (wv == 0) {
      f32x4 qc = {0.f,0.f,0.f,0.f};
#pragma unroll
      for (int s = 0; s < 2; s++) qc = MFMA(hha[s], ldg8(fc2e + lrow*64 + s*32 + lk8), qc);
#pragma unroll
      for (int r = 0; r < 4; r++) {
        int n = n0 + lr4 + r;
        if (lrow < 6)       qout[n*17 + lrow] = qc[r] + fc2_b[lrow];
        else if (lrow == 6) hb[n] = qc[r];
      }
    }
  }
}

// ================= kattack: 8 agents/block; 2 stacks; in-register epilogue dots
__global__ __launch_bounds__(256) void kattack(
    const float* __restrict__ en_feats, const unsigned short* __restrict__ ws,
    const float* __restrict__ how_bin, const float* __restrict__ how_bres,
    const float* __restrict__ hob_bin, const float* __restrict__ hob_bres,
    const unsigned short* __restrict__ g_bf, const float* __restrict__ hbuf,
    const float* __restrict__ hob_wout, const float* __restrict__ hob_bout,
    float* __restrict__ qout)
{
  __shared__ __align__(16) char smem[SMEMB];
  const int t = threadIdx.x;
  const int l = t & 63, wv = t >> 6;
  const int lrow = l & 15, gq = l >> 4;
  const int blk = blockIdx.x;
  const float* feats = en_feats + (long)blk * 880;
  const int tis[2] = {wv, wv + 4};

  stage_x8(feats, 88, smem);
  __syncthreads();   // the only barrier

  f32x4 hval[2][4];

  // ---- hob stack -> qB per row, from registers
  stack8(smem, 6, ws + OFF_WHOB, hob_bin, hob_bres, hval);
  f32x4 hw[4];
#pragma unroll
  for (int mt = 0; mt < 4; mt++) hw[mt] = *(const f32x4*)(hob_wout + mt*16 + gq*4);
  float qbv[2] = {0.f, 0.f};
#pragma unroll
  for (int tt = 0; tt < 2; tt++) {
    if (tis[tt] < 6) {
      float s = 0.f;
#pragma unroll
      for (int mt = 0; mt < 4; mt++)
#pragma unroll
        for (int r = 0; r < 4; r++) s += hval[tt][mt][r] * hw[mt][r];
      s += __shfl_xor(s, 16, 64);
      s += __shfl_xor(s, 32, 64);
      qbv[tt] = s;
    }
  }

  // ---- how stack -> q_attack
  stack8(smem, 6, ws + OFF_WHOW, how_bin, how_bres, hval);
  const float hob_b0 = hob_bout[0];
#pragma unroll
  for (int tt = 0; tt < 2; tt++) {
    if (tis[tt] < 6) {
      int row = tis[tt]*16 + lrow;
      unsigned ag = (unsigned)row / 11u;
      int n = blk*8 + (int)ag;
      float s = 0.f;
#pragma unroll
      for (int mt = 0; mt < 4; mt++) {
        u32x2 gv = *(const u32x2*)(g_bf + (long)n*64 + mt*16 + gq*4);
        s += hval[tt][mt][0] * b2f((unsigned short)(gv.x & 0xFFFF))
           + hval[tt][mt][1] * b2f((unsigned short)(gv.x >> 16))
           + hval[tt][mt][2] * b2f((unsigned short)(gv.y & 0xFFFF))
           + hval[tt][mt][3] * b2f((unsigned short)(gv.y >> 16));
      }
      s += __shfl_xor(s, 16, 64);
      s += __shfl_xor(s, 32, 64);
      if (l < 16 && row < 88) {
        int e = row - (int)ag * 11;
        qout[n*17 + 6 + e] = s + qbv[tt] + hbuf[n] + hob_b0;
      }
    }
  }
}

extern "C" void kernel_launch(void* const* d_in, const int* in_sizes, int n_in,
                              void* d_out, int out_size, void* d_ws, size_t ws_size,
                              hipStream_t stream)
{
  (void)in_sizes; (void)n_in; (void)out_size; (void)ws_size;
  const float* own        = (const float*)d_in[0];
  const float* enemy      = (const float*)d_in[1];
  const float* ally       = (const float*)d_in[2];
  const float* hidden     = (const float*)d_in[3];
  const float* fc1_w      = (const float*)d_in[4];
  const float* fc1_b      = (const float*)d_in[5];
  const float* agent_emb  = (const float*)d_in[6];
  const float* action_emb = (const float*)d_in[7];
  const float* hen_win  = (const float*)d_in[8];  const float* hen_bin  = (const float*)d_in[9];
  const float* hen_wres = (const float*)d_in[10]; const float* hen_bres = (const float*)d_in[11];
  const float* hen_wout = (const float*)d_in[12]; const float* hen_bout = (const float*)d_in[13];
  const float* hal_win  = (const float*)d_in[14]; const float* hal_bin  = (const float*)d_in[15];
  const float* hal_wres = (const float*)d_in[16]; const float* hal_bres = (const float*)d_in[17];
  const float* hal_wout = (const float*)d_in[18]; const float* hal_bout = (const float*)d_in[19];
  const float* gru_wi = (const float*)d_in[20];   const float* gru_wh = (const float*)d_in[21];
  const float* gru_bi = (const float*)d_in[22];   const float* gru_bh = (const float*)d_in[23];
  const float* fc2_w  = (const float*)d_in[24];   const float* fc2_b  = (const float*)d_in[25];
  const float* how_win  = (const float*)d_in[26]; const float* how_bin  = (const float*)d_in[27];
  const float* how_wres = (const float*)d_in[28]; const float* how_bres = (const float*)d_in[29];
  const float* how_wout = (const float*)d_in[30]; const float* how_bout = (const float*)d_in[31];
  const float* hob_win  = (const float*)d_in[32]; const float* hob_bin  = (const float*)d_in[33];
  const float* hob_wres = (const float*)d_in[34]; const float* hob_bres = (const float*)d_in[35];
  const float* hob_wout = (const float*)d_in[36]; const float* hob_bout = (const float*)d_in[37];
  const int* agent_idx   = (const int*)d_in[38];
  const int* last_action = (const int*)d_in[39];

  unsigned short* ws = (unsigned short*)d_ws;
  float* emb_en = (float*)((char*)d_ws + B_EMB_EN);
  float* emb_al = (float*)((char*)d_ws + B_EMB_AL);
  float* hb     = (float*)((char*)d_ws + B_HB);
  unsigned short* g_bf = (unsigned short*)((char*)d_ws + B_GBF);

  float* q  = (float*)d_out;
  float* hh = q + 1024*10*17;

  kprep<<<128, 256, 0, stream>>>(hen_win, hen_wres, hal_win, hal_wres,
      how_win, how_wres, hob_win, hob_wres,
      hen_wout, hen_bout, hal_wout, hal_bout,
      gru_wi, gru_wh, fc1_w, fc2_w, how_bout, how_wout, ws);
  khyp_ea<<<2560, 256, 0, stream>>>(enemy, ally, ws,
      hen_bin, hen_bres, hal_bin, hal_bres, emb_en, emb_al);
  kfused<<<640, 256, 0, stream>>>(own, agent_emb, action_emb, agent_idx, last_action,
      emb_en, emb_al, hidden, ws, fc1_b, gru_bi, gru_bh, fc2_b, q, hh, g_bf, hb);
  kattack<<<1280, 256, 0, stream>>>(enemy, ws, how_bin, how_bres, hob_bin, hob_bres,
      g_bf, hb, hob_wout, hob_bout, q);
}

// Round 9
// 90.588 us; speedup vs baseline: 1.1696x; 1.1123x over previous
//
#include <hip/hip_runtime.h>

#define DI static __device__ __forceinline__

typedef short s16x8 __attribute__((ext_vector_type(8)));
typedef float f32x4 __attribute__((ext_vector_type(4)));
typedef unsigned u32x2 __attribute__((ext_vector_type(2)));

DI unsigned short f2b(float f) {
  union { float f; unsigned u; } v; v.f = f;
  return (unsigned short)((v.u + 0x7FFF + ((v.u >> 16) & 1)) >> 16);  // RNE
}
DI float b2f(unsigned short s) {
  union { unsigned u; float f; } v; v.u = ((unsigned)s) << 16;
  return v.f;
}
DI unsigned cvtpk(float lo, float hi) {
  unsigned r;
  asm("v_cvt_pk_bf16_f32 %0, %1, %2" : "=v"(r) : "v"(lo), "v"(hi));
  return r;
}
DI f32x4 MFMA(s16x8 a, s16x8 b, f32x4 c) {
  return __builtin_amdgcn_mfma_f32_16x16x32_bf16(a, b, c, 0, 0, 0);
}
DI s16x8 ldg8(const unsigned short* p) { return *(const s16x8*)p; }

// ---- ws layout (short offsets) ----
#define OFF_WEN   0        // [2048 winT | 8192 wresT] per stack (W^T, A-operand layout)
#define OFF_WAL   10240
#define OFF_WHOW  20480
#define OFF_WHOB  30720
#define OFF_BGEN  40960    // [21][64][32]
#define OFF_BGAL  83968
#define OFF_WIT   126976   // [192][64]
#define OFF_WHT   139264
#define OFF_FC1T  151552   // [64][32]
#define OFF_FC2E  153600   // [16][64] cols:0-5 fc2, 6 how_bout
#define OFF_HOWT  154624   // [64][64]
#define SH_END    159744
// byte offsets
#define B_EMB_EN  (SH_END*2)
#define B_EMB_AL  (B_EMB_EN + 2621440)
#define B_HB      (B_EMB_AL + 2621440)
#define B_GBF     (B_HB + 40960)

#define PSTR 680
#define HSTR 72          // kfused LDS stride
#define XB2   11264      // x region bytes ([352][16] shorts, swizzled)
#define SMEMB2 56320     // 11264 + 352*128

// swizzled byte offsets (row-XOR on bits 4..6; identical at write & read)
DI int xoff(int row, int byte_in_row) { return ((row*32  + byte_in_row) ^ ((row & 7) << 4)); }
DI int hoff(int row, int byte_in_row) { return XB2 + ((row*128 + byte_in_row) ^ ((row & 7) << 4)); }

// ================= kprep (unchanged layouts) =================
__global__ __launch_bounds__(256) void kprep(
    const float* __restrict__ hen_win, const float* __restrict__ hen_wres,
    const float* __restrict__ hal_win, const float* __restrict__ hal_wres,
    const float* __restrict__ how_win, const float* __restrict__ how_wres,
    const float* __restrict__ hob_win, const float* __restrict__ hob_wres,
    const float* __restrict__ hen_wout, const float* __restrict__ hen_bout,
    const float* __restrict__ hal_wout, const float* __restrict__ hal_bout,
    const float* __restrict__ gru_wi, const float* __restrict__ gru_wh,
    const float* __restrict__ fc1_w, const float* __restrict__ fc2_w,
    const float* __restrict__ how_bout, const float* __restrict__ how_wout,
    unsigned short* __restrict__ ws)
{
  const int gid = blockIdx.x * 256 + threadIdx.x;
  const int gsz = gridDim.x * 256;
  for (int i = gid; i < 4 * 10240; i += gsz) {
    int s = i / 10240, idx = i - s * 10240;
    const float* win  = (s == 0) ? hen_win  : (s == 1) ? hal_win  : (s == 2) ? how_win  : hob_win;
    const float* wres = (s == 0) ? hen_wres : (s == 1) ? hal_wres : (s == 2) ? how_wres : hob_wres;
    float v;
    if (idx < 2048) { int n = idx >> 5, k = idx & 31; v = (k < 10) ? win[k*64 + n] : 0.f; }
    else { int r = idx - 2048; int d = r >> 12; int r2 = r & 4095; int n = r2 >> 6, k = r2 & 63;
           v = wres[d*4096 + k*64 + n]; }
    ws[s * 10240 + idx] = f2b(v);
  }
  for (int i = gid; i < 2 * 43008; i += gsz) {
    int s = i / 43008, idx = i - s * 43008;
    const float* wout = s ? hal_wout : hen_wout;
    const float* bout = s ? hal_bout : hen_bout;
    int kl = idx & 31, n = (idx >> 5) & 63, c = idx >> 11;
    int kfg = c * 32 + kl;
    float v = 0.f;
    if (kfg < 640)      { int k = kfg / 10, f = kfg - k * 10; v = wout[k*640 + f*64 + n]; }
    else if (kfg < 650) { v = bout[(kfg - 640)*64 + n]; }
    ws[(s ? OFF_BGAL : OFF_BGEN) + idx] = f2b(v);
  }
  for (int i = gid; i < 2 * 12288; i += gsz) {
    int s = i / 12288, idx = i - s * 12288;
    int n = idx >> 6, k = idx & 63;
    const float* w = s ? gru_wh : gru_wi;
    ws[(s ? OFF_WHT : OFF_WIT) + idx] = f2b(w[k*192 + n]);
  }
  for (int i = gid; i < 2048; i += gsz) { int n = i >> 5, k = i & 31; ws[OFF_FC1T + i] = f2b(fc1_w[k*64 + n]); }
  for (int i = gid; i < 1024; i += gsz) {
    int n = i >> 6, k = i & 63;
    float v = 0.f; if (n < 6) v = fc2_w[k*6 + n]; else if (n == 6) v = how_bout[k];
    ws[OFF_FC2E + i] = f2b(v);
  }
  for (int i = gid; i < 4096; i += gsz) ws[OFF_HOWT + i] = f2b(how_wout[i]);
}

// ================= stage x: [352 rows][16] bf16, swizzled; rows >= vrows zero
DI void stage_x512(const float* __restrict__ feats, int vrows, char* smem) {
  for (int idx = threadIdx.x; idx < 352*16; idx += 512) {
    int row = idx >> 4, c = idx & 15;
    float v = (row < vrows && c < 10) ? feats[row*10 + c] : 0.f;
    *(unsigned short*)(smem + xoff(row, c*2)) = f2b(v);
  }
}

// ================= stack over row-tiles; wave wv owns tiles {wv, wv+8, wv+16}, layer-major.
// Swapped operands: h^T = W^T x^T. Weights A-operand from global ws; x/h B-operand from
// swizzled LDS. hval: lane(gq,lrow) holds h[n=mt*16+gq*4+r][row=tile*16+lrow].
template<bool WLAST>
DI void stack512(char* smem, int ntiles,
                 const unsigned short* __restrict__ wg,
                 const float* __restrict__ bin, const float* __restrict__ bres,
                 f32x4 (&hval)[3][4])
{
  const int l = threadIdx.x & 63, wv = threadIdx.x >> 6;
  const int lrow = l & 15, gq = l >> 4, lk8 = gq * 8;
  const int tis[3] = {wv, wv + 8, wv + 16};
  {  // layer 1 (K=32; x slots k>=10 garbage, annihilated by zero winT cols)
    s16x8 wf[4]; f32x4 bv[4];
#pragma unroll
    for (int mt = 0; mt < 4; mt++) {
      wf[mt] = ldg8(wg + (mt*16 + lrow)*32 + lk8);
      bv[mt] = *(const f32x4*)(bin + mt*16 + gq*4);
    }
#pragma unroll
    for (int tt = 0; tt < 3; tt++) {
      if (tis[tt] < ntiles) {
        int row = tis[tt]*16 + lrow;
        s16x8 xf = *(const s16x8*)(smem + xoff(row, gq*16));
#pragma unroll
        for (int mt = 0; mt < 4; mt++) {
          f32x4 d = MFMA(wf[mt], xf, f32x4{0.f,0.f,0.f,0.f});
#pragma unroll
          for (int r = 0; r < 4; r++) hval[tt][mt][r] = fmaxf(d[r] + bv[mt][r], 0.f);
          u32x2 pw; pw.x = cvtpk(hval[tt][mt][0], hval[tt][mt][1]);
          pw.y = cvtpk(hval[tt][mt][2], hval[tt][mt][3]);
          *(u32x2*)(smem + hoff(row, (mt*16 + gq*4)*2)) = pw;
        }
      }
    }
  }
#pragma unroll
  for (int d = 0; d < 2; d++) {  // residual layers (K=64 = 2 k-steps)
    const unsigned short* wt = wg + 2048 + d * 4096;
    s16x8 wf0[4], wf1[4]; f32x4 bv[4];
#pragma unroll
    for (int mt = 0; mt < 4; mt++) {
      wf0[mt] = ldg8(wt + (mt*16 + lrow)*64 + lk8);
      wf1[mt] = ldg8(wt + (mt*16 + lrow)*64 + 32 + lk8);
      bv[mt] = *(const f32x4*)(bres + d*64 + mt*16 + gq*4);
    }
#pragma unroll
    for (int tt = 0; tt < 3; tt++) {
      if (tis[tt] < ntiles) {
        int row = tis[tt]*16 + lrow;
        s16x8 b0 = *(const s16x8*)(smem + hoff(row, gq*16));
        s16x8 b1 = *(const s16x8*)(smem + hoff(row, 64 + gq*16));
#pragma unroll
        for (int mt = 0; mt < 4; mt++) {
          f32x4 acc = MFMA(wf0[mt], b0, f32x4{0.f,0.f,0.f,0.f});
          acc = MFMA(wf1[mt], b1, acc);
#pragma unroll
          for (int r = 0; r < 4; r++)
            hval[tt][mt][r] = fmaxf(acc[r] + bv[mt][r], 0.f) + hval[tt][mt][r];
          if (d == 0 || WLAST) {
            u32x2 pw; pw.x = cvtpk(hval[tt][mt][0], hval[tt][mt][1]);
            pw.y = cvtpk(hval[tt][mt][2], hval[tt][mt][3]);
            *(u32x2*)(smem + hoff(row, (mt*16 + gq*4)*2)) = pw;
          }
        }
      }
    }
  }
}

// ================= khyp body: 32 agents/block, 512 threads =================
template<int E>
DI void hyp_body512(const float* __restrict__ feats,
                    const unsigned short* __restrict__ Wg, const unsigned short* __restrict__ Bg,
                    const float* __restrict__ bin, const float* __restrict__ bres,
                    float* __restrict__ emb, char* smem)
{
  const int t = threadIdx.x;
  const int l = t & 63, wv = t >> 6;
  const int lrow = l & 15, gq = l >> 4, lk8 = gq * 8;
  const int rows = 32 * E, ntiles = rows >> 4;   // exact: 352->22, 288->18

  stage_x512(feats, rows, smem);
  __syncthreads();   // bar 1

  f32x4 hval[3][4];
  stack512<true>(smem, ntiles, Wg, bin, bres, hval);
  __syncthreads();   // bar 2: h complete (P-build reads cross-wave rows)

  // ---- P-build: thread = (agent a = t>>4, k-quad kq = t&15); 40 bf16 out per thread
  const int a = t >> 4, kq = t & 15, k0 = kq * 4;
  float acc[4][10];
#pragma unroll
  for (int kk = 0; kk < 4; kk++)
#pragma unroll
    for (int f = 0; f < 10; f++) acc[kk][f] = 0.f;
#pragma unroll
  for (int e = 0; e < E; e++) {
    int row = a * E + e;
    s16x8 xv8 = *(const s16x8*)(smem + xoff(row, 0));
    unsigned xv2 = *(const unsigned*)(smem + xoff(row, 16));
    float xf[10];
#pragma unroll
    for (int f = 0; f < 8; f++) xf[f] = b2f((unsigned short)xv8[f]);
    xf[8] = b2f((unsigned short)(xv2 & 0xFFFF));
    xf[9] = b2f((unsigned short)(xv2 >> 16));
    u32x2 hp = *(const u32x2*)(smem + hoff(row, k0*2));
    float hf[4] = { b2f((unsigned short)(hp.x & 0xFFFF)), b2f((unsigned short)(hp.x >> 16)),
                    b2f((unsigned short)(hp.y & 0xFFFF)), b2f((unsigned short)(hp.y >> 16)) };
#pragma unroll
    for (int kk = 0; kk < 4; kk++)
#pragma unroll
      for (int f = 0; f < 10; f++) acc[kk][f] += hf[kk] * xf[f];
  }
  float sxv = 0.f; int a2 = 0, fx = 0;
  if (t < 320) {
    a2 = t / 10; fx = t - a2 * 10;
    for (int e = 0; e < E; e++) sxv += feats[(a2*E + e)*10 + fx];
  }
  __syncthreads();   // bar 3: all x/h reads done; P2 overlays h region

  unsigned short* P2 = (unsigned short*)(smem + XB2);   // [32][680]
  {
    // kappa-contiguous: 40 bf16 at kappa = k0*10 .. k0*10+39 (value m -> acc[m/10][m%10])
    unsigned* Pw = (unsigned*)(P2 + a*PSTR + k0*10);    // k0*10 = kq*40 -> u32-aligned
#pragma unroll
    for (int m = 0; m < 20; m++) {
      const int v0 = 2*m, v1 = 2*m + 1;
      Pw[m] = cvtpk(acc[v0/10][v0%10], acc[v1/10][v1%10]);
    }
  }
  if (t < 320) P2[a2*PSTR + 640 + fx] = f2b(sxv);
  for (int idx = t; idx < 32*22; idx += 512) { int a3 = idx / 22, c = idx - a3*22; P2[a3*PSTR + 650 + c] = 0; }
  __syncthreads();   // bar 4: P2 ready

  // ---- GEMM: wave wv -> agent-half (wv>>2), n-tile (wv&3); full 16 M-rows
  const int half = wv >> 2, nt = wv & 3;
  f32x4 acc0 = {0.f,0.f,0.f,0.f}, acc1 = {0.f,0.f,0.f,0.f};
  const unsigned short* Bw = Bg + (nt*16 + lrow)*32 + lk8;
  const unsigned short* Pr = P2 + (half*16 + lrow)*PSTR + lk8;
#pragma unroll
  for (int c = 0; c < 21; c++) {
    s16x8 af = *(const s16x8*)&Pr[c*32];
    s16x8 bf = ldg8(Bw + c*2048);
    if (c & 1) acc1 = MFMA(af, bf, acc1); else acc0 = MFMA(af, bf, acc0);
  }
#pragma unroll
  for (int r = 0; r < 4; r++)
    emb[(half*16 + gq*4 + r)*64 + nt*16 + lrow] = acc0[r] + acc1[r];
}

__global__ __launch_bounds__(512) void khyp_ea(
    const float* __restrict__ en_feats, const float* __restrict__ al_feats,
    const unsigned short* __restrict__ ws,
    const float* __restrict__ en_bin, const float* __restrict__ en_bres,
    const float* __restrict__ al_bin, const float* __restrict__ al_bres,
    float* __restrict__ emb_en, float* __restrict__ emb_al)
{
  __shared__ __align__(16) char smem[SMEMB2];
  if (blockIdx.x < 320) {
    int blk = blockIdx.x;
    hyp_body512<11>(en_feats + (long)blk*3520, ws + OFF_WEN, ws + OFF_BGEN,
                    en_bin, en_bres, emb_en + (long)blk*2048, smem);
  } else {
    int blk = blockIdx.x - 320;
    hyp_body512<9>(al_feats + (long)blk*2880, ws + OFF_WAL, ws + OFF_BGAL,
                   al_bin, al_bres, emb_al + (long)blk*2048, smem);
  }
}

// ================= kfused (unchanged; 16 n/block, all MFMA) =================
__global__ __launch_bounds__(256) void kfused(
    const float* __restrict__ own, const float* __restrict__ agent_emb,
    const float* __restrict__ action_emb,
    const int* __restrict__ agent_idx, const int* __restrict__ last_action,
    const float* __restrict__ emb_en, const float* __restrict__ emb_al,
    const float* __restrict__ hidden,
    const unsigned short* __restrict__ ws,
    const float* __restrict__ fc1_b, const float* __restrict__ bi,
    const float* __restrict__ bh, const float* __restrict__ fc2_b,
    float* __restrict__ qout, float* __restrict__ hhout,
    unsigned short* __restrict__ g_bf, float* __restrict__ hb)
{
  __shared__ unsigned short own_lds[16*32];
  __shared__ unsigned short x_lds[16*HSTR];
  __shared__ unsigned short hp_lds[16*HSTR];
  __shared__ unsigned short hh_lds[16*HSTR];
  const int t = threadIdx.x;
  const int l = t & 63, wv = t >> 6;
  const int lrow = l & 15, lk8 = (l >> 4) * 8, lr4 = (l >> 4) * 4;
  const int n0 = blockIdx.x * 16;

  const unsigned short* fc1T = ws + OFF_FC1T;
  const unsigned short* wiT  = ws + OFF_WIT;
  const unsigned short* whT  = ws + OFF_WHT;
  const unsigned short* howT = ws + OFF_HOWT;
  const unsigned short* fc2e = ws + OFF_FC2E;

  for (int i = t; i < 512; i += 256) own_lds[i] = f2b(own[n0*32 + i]);
  for (int i = t; i < 1024; i += 256) hp_lds[(i >> 6)*HSTR + (i & 63)] = f2b(hidden[n0*64 + i]);
  __syncthreads();

  const int j = wv * 16 + lrow;
  {
    s16x8 a0 = *(const s16x8*)&own_lds[lrow*32 + lk8];
    s16x8 b0 = ldg8(fc1T + (wv*16 + lrow)*32 + lk8);
    f32x4 c0 = MFMA(a0, b0, f32x4{0.f,0.f,0.f,0.f});
    float fb = fc1_b[j];
#pragma unroll
    for (int r = 0; r < 4; r++) {
      int aa = lr4 + r; int n = n0 + aa;
      int ai = agent_idx[n], la = last_action[n];
      float v = c0[r] + fb + agent_emb[ai*64 + j] + action_emb[la*64 + j]
              + emb_en[n*64 + j] + emb_al[n*64 + j];
      x_lds[aa*HSTR + j] = f2b(fmaxf(v, 0.f));
    }
  }
  __syncthreads();

  {
    s16x8 xa[2], ha[2];
#pragma unroll
    for (int s = 0; s < 2; s++) {
      xa[s] = *(const s16x8*)&x_lds[lrow*HSTR + s*32 + lk8];
      ha[s] = *(const s16x8*)&hp_lds[lrow*HSTR + s*32 + lk8];
    }
    f32x4 gi[3], gh[3];
#pragma unroll
    for (int g3 = 0; g3 < 3; g3++) { gi[g3] = f32x4{0.f,0.f,0.f,0.f}; gh[g3] = f32x4{0.f,0.f,0.f,0.f}; }
#pragma unroll
    for (int g3 = 0; g3 < 3; g3++) {
      int tl = wv + g3 * 4;
#pragma unroll
      for (int s = 0; s < 2; s++) {
        gi[g3] = MFMA(xa[s], ldg8(wiT + (tl*16 + lrow)*64 + s*32 + lk8), gi[g3]);
        gh[g3] = MFMA(ha[s], ldg8(whT + (tl*16 + lrow)*64 + s*32 + lk8), gh[g3]);
      }
    }
    float bir = bi[j], biz = bi[64 + j], bin_ = bi[128 + j];
    float bhr = bh[j], bhz = bh[64 + j], bhn = bh[128 + j];
#pragma unroll
    for (int r = 0; r < 4; r++) {
      int aa = lr4 + r; int n = n0 + aa;
      float rr = 1.f / (1.f + __expf(-(gi[0][r] + bir + gh[0][r] + bhr)));
      float zz = 1.f / (1.f + __expf(-(gi[1][r] + biz + gh[1][r] + bhz)));
      float nn = tanhf(gi[2][r] + bin_ + rr * (gh[2][r] + bhn));
      float hp = hidden[n*64 + j];
      float hhv = (1.f - zz) * nn + zz * hp;
      hhout[n*64 + j] = hhv;
      hh_lds[aa*HSTR + j] = f2b(hhv);
    }
  }
  __syncthreads();

  {
    s16x8 hha[2];
#pragma unroll
    for (int s = 0; s < 2; s++) hha[s] = *(const s16x8*)&hh_lds[lrow*HSTR + s*32 + lk8];
    f32x4 gc = {0.f,0.f,0.f,0.f};
#pragma unroll
    for (int s = 0; s < 2; s++) gc = MFMA(hha[s], ldg8(howT + (wv*16 + lrow)*64 + s*32 + lk8), gc);
#pragma unroll
    for (int r = 0; r < 4; r++) g_bf[(n0 + lr4 + r)*64 + wv*16 + lrow] = f2b(gc[r]);
    if (wv == 0) {
      f32x4 qc = {0.f,0.f,0.f,0.f};
#pragma unroll
      for (int s = 0; s < 2; s++) qc = MFMA(hha[s], ldg8(fc2e + lrow*64 + s*32 + lk8), qc);
#pragma unroll
      for (int r = 0; r < 4; r++) {
        int n = n0 + lr4 + r;
        if (lrow < 6)       qout[n*17 + lrow] = qc[r] + fc2_b[lrow];
        else if (lrow == 6) hb[n] = qc[r];
      }
    }
  }
}

// ================= kattack: 32 agents/block, 512 threads; 2 stacks; in-reg dots
__global__ __launch_bounds__(512) void kattack(
    const float* __restrict__ en_feats, const unsigned short* __restrict__ ws,
    const float* __restrict__ how_bin, const float* __restrict__ how_bres,
    const float* __restrict__ hob_bin, const float* __restrict__ hob_bres,
    const unsigned short* __restrict__ g_bf, const float* __restrict__ hbuf,
    const float* __restrict__ hob_wout, const float* __restrict__ hob_bout,
    float* __restrict__ qout)
{
  __shared__ __align__(16) char smem[SMEMB2];
  const int t = threadIdx.x;
  const int l = t & 63, wv = t >> 6;
  const int lrow = l & 15, gq = l >> 4;
  const int blk = blockIdx.x;
  const float* feats = en_feats + (long)blk * 3520;
  const int tis[3] = {wv, wv + 8, wv + 16};

  stage_x512(feats, 352, smem);
  __syncthreads();   // the only barrier

  f32x4 hval[3][4];

  // ---- hob stack -> qB per row, from registers
  stack512<false>(smem, 22, ws + OFF_WHOB, hob_bin, hob_bres, hval);
  f32x4 hw[4];
#pragma unroll
  for (int mt = 0; mt < 4; mt++) hw[mt] = *(const f32x4*)(hob_wout + mt*16 + gq*4);
  float qbv[3] = {0.f, 0.f, 0.f};
#pragma unroll
  for (int tt = 0; tt < 3; tt++) {
    if (tis[tt] < 22) {
      float s = 0.f;
#pragma unroll
      for (int mt = 0; mt < 4; mt++)
#pragma unroll
        for (int r = 0; r < 4; r++) s += hval[tt][mt][r] * hw[mt][r];
      s += __shfl_xor(s, 16, 64);
      s += __shfl_xor(s, 32, 64);
      qbv[tt] = s;
    }
  }

  // ---- how stack -> q_attack
  stack512<false>(smem, 22, ws + OFF_WHOW, how_bin, how_bres, hval);
  const float hob_b0 = hob_bout[0];
#pragma unroll
  for (int tt = 0; tt < 3; tt++) {
    if (tis[tt] < 22) {
      int row = tis[tt]*16 + lrow;
      unsigned ag = (unsigned)row / 11u;
      int n = blk*32 + (int)ag;
      float s = 0.f;
#pragma unroll
      for (int mt = 0; mt < 4; mt++) {
        u32x2 gv = *(const u32x2*)(g_bf + (long)n*64 + mt*16 + gq*4);
        s += hval[tt][mt][0] * b2f((unsigned short)(gv.x & 0xFFFF))
           + hval[tt][mt][1] * b2f((unsigned short)(gv.x >> 16))
           + hval[tt][mt][2] * b2f((unsigned short)(gv.y & 0xFFFF))
           + hval[tt][mt][3] * b2f((unsigned short)(gv.y >> 16));
      }
      s += __shfl_xor(s, 16, 64);
      s += __shfl_xor(s, 32, 64);
      if (l < 16) {
        int e = row - (int)ag * 11;
        qout[n*17 + 6 + e] = s + qbv[tt] + hbuf[n] + hob_b0;
      }
    }
  }
}

extern "C" void kernel_launch(void* const* d_in, const int* in_sizes, int n_in,
                              void* d_out, int out_size, void* d_ws, size_t ws_size,
                              hipStream_t stream)
{
  (void)in_sizes; (void)n_in; (void)out_size; (void)ws_size;
  const float* own        = (const float*)d_in[0];
  const float* enemy      = (const float*)d_in[1];
  const float* ally       = (const float*)d_in[2];
  const float* hidden     = (const float*)d_in[3];
  const float* fc1_w      = (const float*)d_in[4];
  const float* fc1_b      = (const float*)d_in[5];
  const float* agent_emb  = (const float*)d_in[6];
  const float* action_emb = (const float*)d_in[7];
  const float* hen_win  = (const float*)d_in[8];  const float* hen_bin  = (const float*)d_in[9];
  const float* hen_wres = (const float*)d_in[10]; const float* hen_bres = (const float*)d_in[11];
  const float* hen_wout = (const float*)d_in[12]; const float* hen_bout = (const float*)d_in[13];
  const float* hal_win  = (const float*)d_in[14]; const float* hal_bin  = (const float*)d_in[15];
  const float* hal_wres = (const float*)d_in[16]; const float* hal_bres = (const float*)d_in[17];
  const float* hal_wout = (const float*)d_in[18]; const float* hal_bout = (const float*)d_in[19];
  const float* gru_wi = (const float*)d_in[20];   const float* gru_wh = (const float*)d_in[21];
  const float* gru_bi = (const float*)d_in[22];   const float* gru_bh = (const float*)d_in[23];
  const float* fc2_w  = (const float*)d_in[24];   const float* fc2_b  = (const float*)d_in[25];
  const float* how_win  = (const float*)d_in[26]; const float* how_bin  = (const float*)d_in[27];
  const float* how_wres = (const float*)d_in[28]; const float* how_bres = (const float*)d_in[29];
  const float* how_wout = (const float*)d_in[30]; const float* how_bout = (const float*)d_in[31];
  const float* hob_win  = (const float*)d_in[32]; const float* hob_bin  = (const float*)d_in[33];
  const float* hob_wres = (const float*)d_in[34]; const float* hob_bres = (const float*)d_in[35];
  const float* hob_wout = (const float*)d_in[36]; const float* hob_bout = (const float*)d_in[37];
  const int* agent_idx   = (const int*)d_in[38];
  const int* last_action = (const int*)d_in[39];

  unsigned short* ws = (unsigned short*)d_ws;
  float* emb_en = (float*)((char*)d_ws + B_EMB_EN);
  float* emb_al = (float*)((char*)d_ws + B_EMB_AL);
  float* hb     = (float*)((char*)d_ws + B_HB);
  unsigned short* g_bf = (unsigned short*)((char*)d_ws + B_GBF);

  float* q  = (float*)d_out;
  float* hh = q + 1024*10*17;

  kprep<<<128, 256, 0, stream>>>(hen_win, hen_wres, hal_win, hal_wres,
      how_win, how_wres, hob_win, hob_wres,
      hen_wout, hen_bout, hal_wout, hal_bout,
      gru_wi, gru_wh, fc1_w, fc2_w, how_bout, how_wout, ws);
  khyp_ea<<<640, 512, 0, stream>>>(enemy, ally, ws,
      hen_bin, hen_bres, hal_bin, hal_bres, emb_en, emb_al);
  kfused<<<640, 256, 0, stream>>>(own, agent_emb, action_emb, agent_idx, last_action,
      emb_en, emb_al, hidden, ws, fc1_b, gru_bi, gru_bh, fc2_b, q, hh, g_bf, hb);
  kattack<<<320, 512, 0, stream>>>(enemy, ws, how_bin, how_bres, hob_bin, hob_bres,
      g_bf, hb, hob_wout, hob_bout, q);
}

// Round 10
// 83.172 us; speedup vs baseline: 1.2739x; 1.0892x over previous
//
#include <hip/hip_runtime.h>

#define DI static __device__ __forceinline__

typedef short s16x8 __attribute__((ext_vector_type(8)));
typedef float f32x4 __attribute__((ext_vector_type(4)));
typedef unsigned u32x2 __attribute__((ext_vector_type(2)));

DI unsigned short f2b(float f) {
  union { float f; unsigned u; } v; v.f = f;
  return (unsigned short)((v.u + 0x7FFF + ((v.u >> 16) & 1)) >> 16);  // RNE
}
DI float b2f(unsigned short s) {
  union { unsigned u; float f; } v; v.u = ((unsigned)s) << 16;
  return v.f;
}
DI unsigned cvtpk(float lo, float hi) {
  unsigned r;
  asm("v_cvt_pk_bf16_f32 %0, %1, %2" : "=v"(r) : "v"(lo), "v"(hi));
  return r;
}
DI f32x4 MFMA(s16x8 a, s16x8 b, f32x4 c) {
  return __builtin_amdgcn_mfma_f32_16x16x32_bf16(a, b, c, 0, 0, 0);
}
DI s16x8 ldg8(const unsigned short* p) { return *(const s16x8*)p; }

// ---- ws layout (short offsets for weights) ----
#define OFF_WEN   0        // [2048 winT | 8192 wresT] per stack (W^T, A-operand layout)
#define OFF_WAL   10240
#define OFF_WHOW  20480
#define OFF_WHOB  30720
#define OFF_BGEN  40960    // [21][64][32]
#define OFF_BGAL  83968
#define OFF_WIT   126976   // [192][64]
#define OFF_WHT   139264
#define OFF_FC1T  151552   // [64][32]
#define OFF_FC2E  153600   // [16][64] cols:0-5 fc2, 6 how_bout
#define OFF_HOWT  154624   // [64][64]
#define SH_END    159744
// byte offsets
#define B_EMB_EN  (SH_END*2)                 // [10240][64] bf16
#define B_EMB_AL  (B_EMB_EN + 1310720)       // [10240][64] bf16
#define B_HHOW    (B_EMB_AL + 1310720)       // [112640][64] bf16
#define B_QB      (B_HHOW + 14417920)        // [112640] f32 (qB + hob_bout folded)

#define XSTR 40
#define HSTR 72
#define PSTR 680

// ================= kprep =================
__global__ __launch_bounds__(256) void kprep(
    const float* __restrict__ hen_win, const float* __restrict__ hen_wres,
    const float* __restrict__ hal_win, const float* __restrict__ hal_wres,
    const float* __restrict__ how_win, const float* __restrict__ how_wres,
    const float* __restrict__ hob_win, const float* __restrict__ hob_wres,
    const float* __restrict__ hen_wout, const float* __restrict__ hen_bout,
    const float* __restrict__ hal_wout, const float* __restrict__ hal_bout,
    const float* __restrict__ gru_wi, const float* __restrict__ gru_wh,
    const float* __restrict__ fc1_w, const float* __restrict__ fc2_w,
    const float* __restrict__ how_bout, const float* __restrict__ how_wout,
    unsigned short* __restrict__ ws)
{
  const int gid = blockIdx.x * 256 + threadIdx.x;
  const int gsz = gridDim.x * 256;
  for (int i = gid; i < 4 * 10240; i += gsz) {
    int s = i / 10240, idx = i - s * 10240;
    const float* win  = (s == 0) ? hen_win  : (s == 1) ? hal_win  : (s == 2) ? how_win  : hob_win;
    const float* wres = (s == 0) ? hen_wres : (s == 1) ? hal_wres : (s == 2) ? how_wres : hob_wres;
    float v;
    if (idx < 2048) { int n = idx >> 5, k = idx & 31; v = (k < 10) ? win[k*64 + n] : 0.f; }
    else { int r = idx - 2048; int d = r >> 12; int r2 = r & 4095; int n = r2 >> 6, k = r2 & 63;
           v = wres[d*4096 + k*64 + n]; }
    ws[s * 10240 + idx] = f2b(v);
  }
  for (int i = gid; i < 2 * 43008; i += gsz) {
    int s = i / 43008, idx = i - s * 43008;
    const float* wout = s ? hal_wout : hen_wout;
    const float* bout = s ? hal_bout : hen_bout;
    int kl = idx & 31, n = (idx >> 5) & 63, c = idx >> 11;
    int kfg = c * 32 + kl;
    float v = 0.f;
    if (kfg < 640)      { int k = kfg / 10, f = kfg - k * 10; v = wout[k*640 + f*64 + n]; }
    else if (kfg < 650) { v = bout[(kfg - 640)*64 + n]; }
    ws[(s ? OFF_BGAL : OFF_BGEN) + idx] = f2b(v);
  }
  for (int i = gid; i < 2 * 12288; i += gsz) {
    int s = i / 12288, idx = i - s * 12288;
    int n = idx >> 6, k = idx & 63;
    const float* w = s ? gru_wh : gru_wi;
    ws[(s ? OFF_WHT : OFF_WIT) + idx] = f2b(w[k*192 + n]);
  }
  for (int i = gid; i < 2048; i += gsz) { int n = i >> 5, k = i & 31; ws[OFF_FC1T + i] = f2b(fc1_w[k*64 + n]); }
  for (int i = gid; i < 1024; i += gsz) {
    int n = i >> 6, k = i & 63;
    float v = 0.f; if (n < 6) v = fc2_w[k*6 + n]; else if (n == 6) v = how_bout[k];
    ws[OFF_FC2E + i] = f2b(v);
  }
  for (int i = gid; i < 4096; i += gsz) ws[OFF_HOWT + i] = f2b(how_wout[i]);
}

// ================= stack_batch (R5-proven): h^T = W^T x^T, TMAX tiles/wave, layer-major
template<int TMAX, bool WLAST>
DI void stack_batch(const unsigned short* __restrict__ x_lds,
                    unsigned short* const (&hbp)[TMAX], const int (&tis)[TMAX], int NT,
                    const unsigned short* __restrict__ wg,
                    const float* __restrict__ bin, const float* __restrict__ bres,
                    f32x4 (&hval)[TMAX][4])
{
  const int l = threadIdx.x & 63;
  const int lrow = l & 15, gq = l >> 4, lk8 = gq * 8;
  {
    s16x8 wf[4]; f32x4 bv[4];
#pragma unroll
    for (int mt = 0; mt < 4; mt++) {
      wf[mt] = ldg8(wg + (mt*16 + lrow)*32 + lk8);
      bv[mt] = *(const f32x4*)(bin + mt*16 + gq*4);
    }
#pragma unroll
    for (int tt = 0; tt < TMAX; tt++) {
      if (tis[tt] < NT) {
        s16x8 xf = *(const s16x8*)&x_lds[(tis[tt]*16 + lrow)*XSTR + lk8];
#pragma unroll
        for (int mt = 0; mt < 4; mt++) {
          f32x4 d = MFMA(wf[mt], xf, f32x4{0.f,0.f,0.f,0.f});
#pragma unroll
          for (int r = 0; r < 4; r++) hval[tt][mt][r] = fmaxf(d[r] + bv[mt][r], 0.f);
        }
        unsigned short* wr = hbp[tt] + lrow*HSTR;
#pragma unroll
        for (int mt = 0; mt < 4; mt++) {
          u32x2 pw;
          pw.x = cvtpk(hval[tt][mt][0], hval[tt][mt][1]);
          pw.y = cvtpk(hval[tt][mt][2], hval[tt][mt][3]);
          *(u32x2*)&wr[mt*16 + gq*4] = pw;
        }
      }
    }
  }
#pragma unroll
  for (int d = 0; d < 2; d++) {
    const unsigned short* wt = wg + 2048 + d * 4096;
    s16x8 wf[4][2]; f32x4 bv[4];
#pragma unroll
    for (int mt = 0; mt < 4; mt++) {
      wf[mt][0] = ldg8(wt + (mt*16 + lrow)*64 + lk8);
      wf[mt][1] = ldg8(wt + (mt*16 + lrow)*64 + 32 + lk8);
      bv[mt] = *(const f32x4*)(bres + d*64 + mt*16 + gq*4);
    }
#pragma unroll
    for (int tt = 0; tt < TMAX; tt++) {
      if (tis[tt] < NT) {
        const unsigned short* hr = hbp[tt] + lrow*HSTR;
        s16x8 b0 = *(const s16x8*)&hr[lk8];
        s16x8 b1 = *(const s16x8*)&hr[32 + lk8];
#pragma unroll
        for (int mt = 0; mt < 4; mt++) {
          f32x4 a = MFMA(wf[mt][0], b0, f32x4{0.f,0.f,0.f,0.f});
          a = MFMA(wf[mt][1], b1, a);
#pragma unroll
          for (int r = 0; r < 4; r++)
            hval[tt][mt][r] = fmaxf(a[r] + bv[mt][r], 0.f) + hval[tt][mt][r];
        }
        if (d == 0 || WLAST) {
          unsigned short* wr = hbp[tt] + lrow*HSTR;
#pragma unroll
          for (int mt = 0; mt < 4; mt++) {
            u32x2 pw;
            pw.x = cvtpk(hval[tt][mt][0], hval[tt][mt][1]);
            pw.y = cvtpk(hval[tt][mt][2], hval[tt][mt][3]);
            *(u32x2*)&wr[mt*16 + gq*4] = pw;
          }
        }
      }
    }
  }
}

// ================= hyp body (R5-proven, emb -> bf16): 16 agents/block
template<int E>
DI void hyp_body16(const float* __restrict__ feats,
                   const unsigned short* __restrict__ Wg, const unsigned short* __restrict__ Bg,
                   const float* __restrict__ bin, const float* __restrict__ bres,
                   unsigned short* __restrict__ emb, char* smem)
{
  unsigned short* x_lds = (unsigned short*)smem;            // [16E][40]
  unsigned short* h_lds = (unsigned short*)(smem + 14080);  // [16E][72]
  unsigned short* P     = (unsigned short*)smem;            // [16][680] overlay
  const int t = threadIdx.x;
  const int l = t & 63, wv = t >> 6;
  const int lrow = l & 15, gq = l >> 4, lk8 = gq * 8, lr4 = gq * 4;

  for (int idx = t; idx < E * 512; idx += 256) {
    int row = idx >> 5, c = idx & 31;
    x_lds[row*XSTR + c] = (c < 10) ? f2b(feats[row*10 + c]) : (unsigned short)0;
  }
  __syncthreads();

  int tis[3] = {wv, wv + 4, wv + 8};
  unsigned short* hbp[3] = { h_lds + (wv)*16*HSTR, h_lds + (wv+4)*16*HSTR, h_lds + (wv+8)*16*HSTR };
  f32x4 hval[3][4];
  stack_batch<3, true>(x_lds, hbp, tis, E, Wg, bin, bres, hval);
  __syncthreads();   // h complete across waves

  // ---- P-build: thread = (agent a, k-quad kq)
  const int a = t >> 4, kq = t & 15, k0 = kq * 4;
  float acc[4][10];
#pragma unroll
  for (int kk = 0; kk < 4; kk++)
#pragma unroll
    for (int f = 0; f < 10; f++) acc[kk][f] = 0.f;
#pragma unroll
  for (int e = 0; e < E; e++) {
    int row = a * E + e;
    const unsigned short* xr = x_lds + row * XSTR;
    s16x8 xv8 = *(const s16x8*)xr;
    unsigned xv2 = *(const unsigned*)(xr + 8);
    float xf[10];
#pragma unroll
    for (int f = 0; f < 8; f++) xf[f] = b2f((unsigned short)xv8[f]);
    xf[8] = b2f((unsigned short)(xv2 & 0xFFFF));
    xf[9] = b2f((unsigned short)(xv2 >> 16));
    u32x2 hp = *(const u32x2*)&h_lds[row*HSTR + k0];
    float hf[4] = { b2f((unsigned short)(hp.x & 0xFFFF)), b2f((unsigned short)(hp.x >> 16)),
                    b2f((unsigned short)(hp.y & 0xFFFF)), b2f((unsigned short)(hp.y >> 16)) };
#pragma unroll
    for (int kk = 0; kk < 4; kk++)
#pragma unroll
      for (int f = 0; f < 10; f++) acc[kk][f] += hf[kk] * xf[f];
  }
  float sxv = 0.f; int a2 = 0, fx = 0;
  if (t < 160) {
    a2 = t / 10; fx = t - a2 * 10;
    for (int e = 0; e < E; e++) sxv += feats[(a2*E + e)*10 + fx];
  }
  __syncthreads();   // all x/h reads done; P overlays

  u32x2* Pw = (u32x2*)(P + a*PSTR + k0*10);
#pragma unroll
  for (int m = 0; m < 10; m++) {
    const int s0 = 4*m, s1 = 4*m+1, s2 = 4*m+2, s3 = 4*m+3;
    u32x2 pw;
    pw.x = cvtpk(acc[s0/10][s0%10], acc[s1/10][s1%10]);
    pw.y = cvtpk(acc[s2/10][s2%10], acc[s3/10][s3%10]);
    Pw[m] = pw;
  }
  if (t < 160) P[a2*PSTR + 640 + fx] = f2b(sxv);
  for (int i = t; i < 352; i += 256) { int a3 = i / 22, c = i - a3*22; P[a3*PSTR + 650 + c] = 0; }
  __syncthreads();   // P ready

  // ---- GEMM: wave wv owns n-tile wv; M = 16 agents; B direct from global
  f32x4 acc0 = {0.f,0.f,0.f,0.f}, acc1 = {0.f,0.f,0.f,0.f};
  const unsigned short* Bw = Bg + (wv*16 + lrow)*32 + lk8;
#pragma unroll
  for (int c = 0; c < 21; c++) {
    s16x8 af = *(const s16x8*)&P[lrow*PSTR + c*32 + lk8];
    s16x8 bf = ldg8(Bw + c*2048);
    if (c & 1) acc1 = MFMA(af, bf, acc1); else acc0 = MFMA(af, bf, acc0);
  }
#pragma unroll
  for (int r = 0; r < 4; r++)
    emb[(lr4 + r)*64 + wv*16 + lrow] = f2b(acc0[r] + acc1[r]);
}

// ================= attack stacks (R5 kattack minus the g-dot): export h_how + qB
DI void attack_stacks(int blk, const float* __restrict__ en_feats,
                      const unsigned short* __restrict__ ws,
                      const float* __restrict__ how_bin, const float* __restrict__ how_bres,
                      const float* __restrict__ hob_bin, const float* __restrict__ hob_bres,
                      const float* __restrict__ hob_wout, float hob_b0,
                      unsigned short* __restrict__ hhow, float* __restrict__ qB, char* smem)
{
  unsigned short* x_lds = (unsigned short*)smem;
  unsigned short* scr   = (unsigned short*)(smem + 14080);
  const int t = threadIdx.x;
  const int l = t & 63, wv = t >> 6;
  const int lrow = l & 15, gq = l >> 4;
  const float* feats = en_feats + (long)blk * 1760;

  for (int idx = t; idx < 176*32; idx += 256) {
    int row = idx >> 5, c = idx & 31;
    x_lds[row*XSTR + c] = (c < 10) ? f2b(feats[row*10 + c]) : (unsigned short)0;
  }
  __syncthreads();   // the only barrier

  int tis[3] = {wv, wv + 4, wv + 8};
  unsigned short* hbp[3] = { scr + (wv*3+0)*16*HSTR, scr + (wv*3+1)*16*HSTR, scr + (wv*3+2)*16*HSTR };
  f32x4 hval[3][4];

  // ---- hob stack -> qB (from f32 regs), fold hob_b0
  stack_batch<3, false>(x_lds, hbp, tis, 11, ws + OFF_WHOB, hob_bin, hob_bres, hval);
  f32x4 hw[4];
#pragma unroll
  for (int mt = 0; mt < 4; mt++) hw[mt] = *(const f32x4*)(hob_wout + mt*16 + gq*4);
#pragma unroll
  for (int tt = 0; tt < 3; tt++) {
    if (tis[tt] < 11) {
      float s = 0.f;
#pragma unroll
      for (int mt = 0; mt < 4; mt++)
#pragma unroll
        for (int r = 0; r < 4; r++) s += hval[tt][mt][r] * hw[mt][r];
      s += __shfl_xor(s, 16, 64);
      s += __shfl_xor(s, 32, 64);
      if (l < 16) qB[blk*176 + tis[tt]*16 + lrow] = s + hob_b0;
    }
  }

  // ---- how stack -> export h rows (bf16) straight from registers
  stack_batch<3, false>(x_lds, hbp, tis, 11, ws + OFF_WHOW, how_bin, how_bres, hval);
#pragma unroll
  for (int tt = 0; tt < 3; tt++) {
    if (tis[tt] < 11) {
      long row = (long)blk*176 + tis[tt]*16 + lrow;
      unsigned short* wr = hhow + row*64;
#pragma unroll
      for (int mt = 0; mt < 4; mt++) {
        u32x2 pw;
        pw.x = cvtpk(hval[tt][mt][0], hval[tt][mt][1]);
        pw.y = cvtpk(hval[tt][mt][2], hval[tt][mt][3]);
        *(u32x2*)&wr[mt*16 + gq*4] = pw;
      }
    }
  }
}

__global__ __launch_bounds__(256) void khyp_all(
    const float* __restrict__ en_feats, const float* __restrict__ al_feats,
    const unsigned short* __restrict__ ws,
    const float* __restrict__ en_bin, const float* __restrict__ en_bres,
    const float* __restrict__ al_bin, const float* __restrict__ al_bres,
    const float* __restrict__ how_bin, const float* __restrict__ how_bres,
    const float* __restrict__ hob_bin, const float* __restrict__ hob_bres,
    const float* __restrict__ hob_wout, const float* __restrict__ hob_bout,
    unsigned short* __restrict__ emb_en, unsigned short* __restrict__ emb_al,
    unsigned short* __restrict__ hhow, float* __restrict__ qB)
{
  __shared__ __align__(16) char smem[41728];
  if (blockIdx.x < 640) {
    int blk = blockIdx.x;
    hyp_body16<11>(en_feats + (long)blk*1760, ws + OFF_WEN, ws + OFF_BGEN,
                   en_bin, en_bres, emb_en + (long)blk*1024, smem);
  } else if (blockIdx.x < 1280) {
    int blk = blockIdx.x - 640;
    hyp_body16<9>(al_feats + (long)blk*1440, ws + OFF_WAL, ws + OFF_BGAL,
                  al_bin, al_bres, emb_al + (long)blk*1024, smem);
  } else {
    attack_stacks(blockIdx.x - 1280, en_feats, ws, how_bin, how_bres,
                  hob_bin, hob_bres, hob_wout, hob_bout[0], hhow, qB, smem);
  }
}

// ================= kfused2: fc1+embeds+GRU+fc2 + g/hb in LDS + attack-dot epilogue
__global__ __launch_bounds__(256) void kfused2(
    const float* __restrict__ own, const float* __restrict__ agent_emb,
    const float* __restrict__ action_emb,
    const int* __restrict__ agent_idx, const int* __restrict__ last_action,
    const unsigned short* __restrict__ emb_en, const unsigned short* __restrict__ emb_al,
    const float* __restrict__ hidden,
    const unsigned short* __restrict__ ws,
    const float* __restrict__ fc1_b, const float* __restrict__ bi,
    const float* __restrict__ bh, const float* __restrict__ fc2_b,
    const unsigned short* __restrict__ hhow, const float* __restrict__ qB,
    float* __restrict__ qout, float* __restrict__ hhout)
{
  __shared__ unsigned short own_lds[16*32];
  __shared__ unsigned short x_lds[16*HSTR];
  __shared__ unsigned short hp_lds[16*HSTR];
  __shared__ unsigned short hh_lds[16*HSTR];
  __shared__ unsigned short g_lds[16*HSTR];
  __shared__ float hb_lds[16];
  const int t = threadIdx.x;
  const int l = t & 63, wv = t >> 6;
  const int lrow = l & 15, gq = l >> 4, lk8 = gq * 8, lr4 = gq * 4;
  const int n0 = blockIdx.x * 16;

  const unsigned short* fc1T = ws + OFF_FC1T;
  const unsigned short* wiT  = ws + OFF_WIT;
  const unsigned short* whT  = ws + OFF_WHT;
  const unsigned short* howT = ws + OFF_HOWT;
  const unsigned short* fc2e = ws + OFF_FC2E;

  for (int i = t; i < 512; i += 256) own_lds[i] = f2b(own[n0*32 + i]);
  for (int i = t; i < 1024; i += 256) hp_lds[(i >> 6)*HSTR + (i & 63)] = f2b(hidden[n0*64 + i]);
  __syncthreads();

  const int j = wv * 16 + lrow;
  {  // fc1 + gathers -> x
    s16x8 a0 = *(const s16x8*)&own_lds[lrow*32 + lk8];
    s16x8 b0 = ldg8(fc1T + (wv*16 + lrow)*32 + lk8);
    f32x4 c0 = MFMA(a0, b0, f32x4{0.f,0.f,0.f,0.f});
    float fb = fc1_b[j];
#pragma unroll
    for (int r = 0; r < 4; r++) {
      int aa = lr4 + r; int n = n0 + aa;
      int ai = agent_idx[n], la = last_action[n];
      float v = c0[r] + fb + agent_emb[ai*64 + j] + action_emb[la*64 + j]
              + b2f(emb_en[(long)n*64 + j]) + b2f(emb_al[(long)n*64 + j]);
      x_lds[aa*HSTR + j] = f2b(fmaxf(v, 0.f));
    }
  }
  __syncthreads();

  {  // GRU
    s16x8 xa[2], ha[2];
#pragma unroll
    for (int s = 0; s < 2; s++) {
      xa[s] = *(const s16x8*)&x_lds[lrow*HSTR + s*32 + lk8];
      ha[s] = *(const s16x8*)&hp_lds[lrow*HSTR + s*32 + lk8];
    }
    f32x4 gi[3], gh[3];
#pragma unroll
    for (int g3 = 0; g3 < 3; g3++) { gi[g3] = f32x4{0.f,0.f,0.f,0.f}; gh[g3] = f32x4{0.f,0.f,0.f,0.f}; }
#pragma unroll
    for (int g3 = 0; g3 < 3; g3++) {
      int tl = wv + g3 * 4;
#pragma unroll
      for (int s = 0; s < 2; s++) {
        gi[g3] = MFMA(xa[s], ldg8(wiT + (tl*16 + lrow)*64 + s*32 + lk8), gi[g3]);
        gh[g3] = MFMA(ha[s], ldg8(whT + (tl*16 + lrow)*64 + s*32 + lk8), gh[g3]);
      }
    }
    float bir = bi[j], biz = bi[64 + j], bin_ = bi[128 + j];
    float bhr = bh[j], bhz = bh[64 + j], bhn = bh[128 + j];
#pragma unroll
    for (int r = 0; r < 4; r++) {
      int aa = lr4 + r; int n = n0 + aa;
      float rr = 1.f / (1.f + __expf(-(gi[0][r] + bir + gh[0][r] + bhr)));
      float zz = 1.f / (1.f + __expf(-(gi[1][r] + biz + gh[1][r] + bhz)));
      float nn = tanhf(gi[2][r] + bin_ + rr * (gh[2][r] + bhn));
      float hp = hidden[n*64 + j];
      float hhv = (1.f - zz) * nn + zz * hp;
      hhout[n*64 + j] = hhv;
      hh_lds[aa*HSTR + j] = f2b(hhv);
    }
  }
  __syncthreads();

  {  // g = hh @ howT (to LDS) ; fc2ext (q_normal + hb to LDS)
    s16x8 hha[2];
#pragma unroll
    for (int s = 0; s < 2; s++) hha[s] = *(const s16x8*)&hh_lds[lrow*HSTR + s*32 + lk8];
    f32x4 gc = {0.f,0.f,0.f,0.f};
#pragma unroll
    for (int s = 0; s < 2; s++) gc = MFMA(hha[s], ldg8(howT + (wv*16 + lrow)*64 + s*32 + lk8), gc);
#pragma unroll
    for (int r = 0; r < 4; r++) g_lds[(lr4 + r)*HSTR + wv*16 + lrow] = f2b(gc[r]);
    if (wv == 0) {
      f32x4 qc = {0.f,0.f,0.f,0.f};
#pragma unroll
      for (int s = 0; s < 2; s++) qc = MFMA(hha[s], ldg8(fc2e + lrow*64 + s*32 + lk8), qc);
#pragma unroll
      for (int r = 0; r < 4; r++) {
        int n = n0 + lr4 + r;
        if (lrow < 6)       qout[n*17 + lrow] = qc[r] + fc2_b[lrow];
        else if (lrow == 6) hb_lds[lr4 + r] = qc[r];
      }
    }
  }
  __syncthreads();

  {  // attack epilogue: C[row][ag] = h_how[row] . g[ag]; keep ag == row/11
    const long rb = (long)blockIdx.x * 176;
#pragma unroll
    for (int tt = 0; tt < 3; tt++) {
      int ti = wv + tt * 4;
      if (ti < 11) {
        const unsigned short* hr = hhow + (rb + ti*16 + lrow)*64;
        s16x8 af0 = ldg8(hr + lk8);
        s16x8 af1 = ldg8(hr + 32 + lk8);
        s16x8 bf0 = *(const s16x8*)&g_lds[lrow*HSTR + lk8];
        s16x8 bf1 = *(const s16x8*)&g_lds[lrow*HSTR + 32 + lk8];
        f32x4 c = MFMA(af0, bf0, f32x4{0.f,0.f,0.f,0.f});
        c = MFMA(af1, bf1, c);
#pragma unroll
        for (int r = 0; r < 4; r++) {
          int rowl = ti*16 + lr4 + r;
          int ag = (unsigned)rowl / 11u;
          if (ag == lrow) {
            int e = rowl - ag * 11;
            int n = n0 + ag;
            qout[n*17 + 6 + e] = c[r] + qB[rb + rowl] + hb_lds[ag];
          }
        }
      }
    }
  }
}

extern "C" void kernel_launch(void* const* d_in, const int* in_sizes, int n_in,
                              void* d_out, int out_size, void* d_ws, size_t ws_size,
                              hipStream_t stream)
{
  (void)in_sizes; (void)n_in; (void)out_size; (void)ws_size;
  const float* own        = (const float*)d_in[0];
  const float* enemy      = (const float*)d_in[1];
  const float* ally       = (const float*)d_in[2];
  const float* hidden     = (const float*)d_in[3];
  const float* fc1_w      = (const float*)d_in[4];
  const float* fc1_b      = (const float*)d_in[5];
  const float* agent_emb  = (const float*)d_in[6];
  const float* action_emb = (const float*)d_in[7];
  const float* hen_win  = (const float*)d_in[8];  const float* hen_bin  = (const float*)d_in[9];
  const float* hen_wres = (const float*)d_in[10]; const float* hen_bres = (const float*)d_in[11];
  const float* hen_wout = (const float*)d_in[12]; const float* hen_bout = (const float*)d_in[13];
  const float* hal_win  = (const float*)d_in[14]; const float* hal_bin  = (const float*)d_in[15];
  const float* hal_wres = (const float*)d_in[16]; const float* hal_bres = (const float*)d_in[17];
  const float* hal_wout = (const float*)d_in[18]; const float* hal_bout = (const float*)d_in[19];
  const float* gru_wi = (const float*)d_in[20];   const float* gru_wh = (const float*)d_in[21];
  const float* gru_bi = (const float*)d_in[22];   const float* gru_bh = (const float*)d_in[23];
  const float* fc2_w  = (const float*)d_in[24];   const float* fc2_b  = (const float*)d_in[25];
  const float* how_win  = (const float*)d_in[26]; const float* how_bin  = (const float*)d_in[27];
  const float* how_wres = (const float*)d_in[28]; const float* how_bres = (const float*)d_in[29];
  const float* how_wout = (const float*)d_in[30]; const float* how_bout = (const float*)d_in[31];
  const float* hob_win  = (const float*)d_in[32]; const float* hob_bin  = (const float*)d_in[33];
  const float* hob_wres = (const float*)d_in[34]; const float* hob_bres = (const float*)d_in[35];
  const float* hob_wout = (const float*)d_in[36]; const float* hob_bout = (const float*)d_in[37];
  const int* agent_idx   = (const int*)d_in[38];
  const int* last_action = (const int*)d_in[39];

  unsigned short* ws = (unsigned short*)d_ws;
  unsigned short* emb_en = (unsigned short*)((char*)d_ws + B_EMB_EN);
  unsigned short* emb_al = (unsigned short*)((char*)d_ws + B_EMB_AL);
  unsigned short* hhow   = (unsigned short*)((char*)d_ws + B_HHOW);
  float*          qB     = (float*)((char*)d_ws + B_QB);

  float* q  = (float*)d_out;
  float* hh = q + 1024*10*17;

  kprep<<<128, 256, 0, stream>>>(hen_win, hen_wres, hal_win, hal_wres,
      how_win, how_wres, hob_win, hob_wres,
      hen_wout, hen_bout, hal_wout, hal_bout,
      gru_wi, gru_wh, fc1_w, fc2_w, how_bout, how_wout, ws);
  khyp_all<<<1920, 256, 0, stream>>>(enemy, ally, ws,
      hen_bin, hen_bres, hal_bin, hal_bres,
      how_bin, how_bres, hob_bin, hob_bres, hob_wout, hob_bout,
      emb_en, emb_al, hhow, qB);
  kfused2<<<640, 256, 0, stream>>>(own, agent_emb, action_emb, agent_idx, last_action,
      emb_en, emb_al, hidden, ws, fc1_b, gru_bi, gru_bh, fc2_b,
      hhow, qB, q, hh);
}

// Round 11
// 78.048 us; speedup vs baseline: 1.3575x; 1.0656x over previous
//
#include <hip/hip_runtime.h>

#define DI static __device__ __forceinline__

typedef short s16x8 __attribute__((ext_vector_type(8)));
typedef float f32x4 __attribute__((ext_vector_type(4)));
typedef unsigned u32x2 __attribute__((ext_vector_type(2)));

DI unsigned short f2b(float f) {
  union { float f; unsigned u; } v; v.f = f;
  return (unsigned short)((v.u + 0x7FFF + ((v.u >> 16) & 1)) >> 16);  // RNE
}
DI float b2f(unsigned short s) {
  union { unsigned u; float f; } v; v.u = ((unsigned)s) << 16;
  return v.f;
}
DI unsigned cvtpk(float lo, float hi) {
  unsigned r;
  asm("v_cvt_pk_bf16_f32 %0, %1, %2" : "=v"(r) : "v"(lo), "v"(hi));
  return r;
}
DI f32x4 MFMA(s16x8 a, s16x8 b, f32x4 c) {
  return __builtin_amdgcn_mfma_f32_16x16x32_bf16(a, b, c, 0, 0, 0);
}
DI s16x8 ldg8(const unsigned short* p) { return *(const s16x8*)p; }

// ---- ws layout (short offsets) ----
#define OFF_WEN   0        // [2048 winT | 8192 wresT] per stack (W^T, A-operand layout)
#define OFF_WAL   10240
#define OFF_WHOW  20480
#define OFF_WHOB  30720
#define OFF_BGEN  40960    // [21][64][32]
#define OFF_BGAL  83968
#define OFF_WIT   126976   // [192][64]
#define OFF_WHT   139264
#define OFF_FC1T  151552   // [64][32]
#define OFF_FC2E  153600   // [16][64] cols:0-5 fc2, 6 how_bout
#define OFF_HOWT  154624   // [64][64]
#define SH_END    159744
// byte offsets
#define B_EMB_EN  (SH_END*2)
#define B_EMB_AL  (B_EMB_EN + 2621440)
#define B_HB      (B_EMB_AL + 2621440)
#define B_GBF     (B_HB + 40960)

#define PSTR 680
#define HSTR 72          // kattack/kfused LDS stride
#define XSTR 40          // kattack x stride (shorts)

// khyp compact slot: x[176][16] swizzled (5632 B) + h[176][64] swizzled (22528 B)
#define SLOT 28160
#define XBC  5632
DI int xoffc(int row, int b) { return ((row*32  + b) ^ ((row & 7) << 4)); }
DI int hoffc(int row, int b) { return XBC + ((row*128 + b) ^ ((row & 7) << 4)); }

// ================= kprep (R5 verbatim) =================
__global__ __launch_bounds__(256) void kprep(
    const float* __restrict__ hen_win, const float* __restrict__ hen_wres,
    const float* __restrict__ hal_win, const float* __restrict__ hal_wres,
    const float* __restrict__ how_win, const float* __restrict__ how_wres,
    const float* __restrict__ hob_win, const float* __restrict__ hob_wres,
    const float* __restrict__ hen_wout, const float* __restrict__ hen_bout,
    const float* __restrict__ hal_wout, const float* __restrict__ hal_bout,
    const float* __restrict__ gru_wi, const float* __restrict__ gru_wh,
    const float* __restrict__ fc1_w, const float* __restrict__ fc2_w,
    const float* __restrict__ how_bout, const float* __restrict__ how_wout,
    unsigned short* __restrict__ ws)
{
  const int gid = blockIdx.x * 256 + threadIdx.x;
  const int gsz = gridDim.x * 256;
  for (int i = gid; i < 4 * 10240; i += gsz) {
    int s = i / 10240, idx = i - s * 10240;
    const float* win  = (s == 0) ? hen_win  : (s == 1) ? hal_win  : (s == 2) ? how_win  : hob_win;
    const float* wres = (s == 0) ? hen_wres : (s == 1) ? hal_wres : (s == 2) ? how_wres : hob_wres;
    float v;
    if (idx < 2048) { int n = idx >> 5, k = idx & 31; v = (k < 10) ? win[k*64 + n] : 0.f; }
    else { int r = idx - 2048; int d = r >> 12; int r2 = r & 4095; int n = r2 >> 6, k = r2 & 63;
           v = wres[d*4096 + k*64 + n]; }
    ws[s * 10240 + idx] = f2b(v);
  }
  for (int i = gid; i < 2 * 43008; i += gsz) {
    int s = i / 43008, idx = i - s * 43008;
    const float* wout = s ? hal_wout : hen_wout;
    const float* bout = s ? hal_bout : hen_bout;
    int kl = idx & 31, n = (idx >> 5) & 63, c = idx >> 11;
    int kfg = c * 32 + kl;
    float v = 0.f;
    if (kfg < 640)      { int k = kfg / 10, f = kfg - k * 10; v = wout[k*640 + f*64 + n]; }
    else if (kfg < 650) { v = bout[(kfg - 640)*64 + n]; }
    ws[(s ? OFF_BGAL : OFF_BGEN) + idx] = f2b(v);
  }
  for (int i = gid; i < 2 * 12288; i += gsz) {
    int s = i / 12288, idx = i - s * 12288;
    int n = idx >> 6, k = idx & 63;
    const float* w = s ? gru_wh : gru_wi;
    ws[(s ? OFF_WHT : OFF_WIT) + idx] = f2b(w[k*192 + n]);
  }
  for (int i = gid; i < 2048; i += gsz) { int n = i >> 5, k = i & 31; ws[OFF_FC1T + i] = f2b(fc1_w[k*64 + n]); }
  for (int i = gid; i < 1024; i += gsz) {
    int n = i >> 6, k = i & 63;
    float v = 0.f; if (n < 6) v = fc2_w[k*6 + n]; else if (n == 6) v = how_bout[k];
    ws[OFF_FC2E + i] = f2b(v);
  }
  for (int i = gid; i < 4096; i += gsz) ws[OFF_HOWT + i] = f2b(how_wout[i]);
}

// ================= khyp: persistent, 2-slot, 16 agents/item =================
DI void stage_item(const float* __restrict__ feats, int vrows, char* sl) {
  for (int idx = threadIdx.x; idx < 176*16; idx += 256) {
    int row = idx >> 4, c = idx & 15;
    float v = (row < vrows && c < 10) ? feats[row*10 + c] : 0.f;
    *(unsigned short*)(sl + xoffc(row, c*2)) = f2b(v);
  }
}

// stack: wave wv owns tiles {wv,wv+4,wv+8}, layer-major; bias preloaded in C
DI void stackP(char* sl, int ntiles, const unsigned short* __restrict__ wg,
               const float* __restrict__ bin, const float* __restrict__ bres)
{
  const int l = threadIdx.x & 63, wv = threadIdx.x >> 6;
  const int lrow = l & 15, gq = l >> 4, lk8 = gq * 8;
  const int tis[3] = {wv, wv + 4, wv + 8};
  f32x4 hval[3][4];
  {  // layer 1 (K=32; x slots k>=10 garbage annihilated by zero winT cols)
    s16x8 wf[4]; f32x4 bv[4];
#pragma unroll
    for (int mt = 0; mt < 4; mt++) {
      wf[mt] = ldg8(wg + (mt*16 + lrow)*32 + lk8);
      bv[mt] = *(const f32x4*)(bin + mt*16 + gq*4);
    }
#pragma unroll
    for (int tt = 0; tt < 3; tt++) {
      if (tis[tt] < ntiles) {
        int row = tis[tt]*16 + lrow;
        s16x8 xf = *(const s16x8*)(sl + xoffc(row, gq*16));
#pragma unroll
        for (int mt = 0; mt < 4; mt++) {
          f32x4 d = MFMA(wf[mt], xf, bv[mt]);
#pragma unroll
          for (int r = 0; r < 4; r++) hval[tt][mt][r] = fmaxf(d[r], 0.f);
          u32x2 pw; pw.x = cvtpk(hval[tt][mt][0], hval[tt][mt][1]);
          pw.y = cvtpk(hval[tt][mt][2], hval[tt][mt][3]);
          *(u32x2*)(sl + hoffc(row, (mt*16 + gq*4)*2)) = pw;
        }
      }
    }
  }
#pragma unroll
  for (int d = 0; d < 2; d++) {  // residual layers (K=64 = 2 k-steps)
    const unsigned short* wt = wg + 2048 + d * 4096;
    s16x8 wf0[4], wf1[4]; f32x4 bv[4];
#pragma unroll
    for (int mt = 0; mt < 4; mt++) {
      wf0[mt] = ldg8(wt + (mt*16 + lrow)*64 + lk8);
      wf1[mt] = ldg8(wt + (mt*16 + lrow)*64 + 32 + lk8);
      bv[mt] = *(const f32x4*)(bres + d*64 + mt*16 + gq*4);
    }
#pragma unroll
    for (int tt = 0; tt < 3; tt++) {
      if (tis[tt] < ntiles) {
        int row = tis[tt]*16 + lrow;
        s16x8 b0 = *(const s16x8*)(sl + hoffc(row, gq*16));
        s16x8 b1 = *(const s16x8*)(sl + hoffc(row, 64 + gq*16));
#pragma unroll
        for (int mt = 0; mt < 4; mt++) {
          f32x4 acc = MFMA(wf0[mt], b0, bv[mt]);
          acc = MFMA(wf1[mt], b1, acc);
#pragma unroll
          for (int r = 0; r < 4; r++)
            hval[tt][mt][r] = fmaxf(acc[r], 0.f) + hval[tt][mt][r];
          u32x2 pw; pw.x = cvtpk(hval[tt][mt][0], hval[tt][mt][1]);
          pw.y = cvtpk(hval[tt][mt][2], hval[tt][mt][3]);
          *(u32x2*)(sl + hoffc(row, (mt*16 + gq*4)*2)) = pw;
        }
      }
    }
  }
}

__global__ __launch_bounds__(256) void khyp_ea(
    const float* __restrict__ en_feats, const float* __restrict__ al_feats,
    const unsigned short* __restrict__ ws,
    const float* __restrict__ en_bin, const float* __restrict__ en_bres,
    const float* __restrict__ al_bin, const float* __restrict__ al_bres,
    float* __restrict__ emb_en, float* __restrict__ emb_al)
{
  __shared__ __align__(16) char smem[2*SLOT];
  const int t = threadIdx.x;
  const int l = t & 63, wv = t >> 6;
  const int lrow = l & 15, gq = l >> 4, lk8 = gq * 8;

  int its[3]; int nit = 0;
  for (int it = blockIdx.x; it < 1280; it += 512) its[nit++] = it;

  {
    int it0 = its[0];
    const float* f0 = (it0 < 640) ? en_feats + (long)it0*1760
                                  : al_feats + (long)(it0-640)*1440;
    stage_item(f0, (it0 < 640) ? 176 : 144, smem);
  }
  __syncthreads();

  for (int i = 0; i < nit; i++) {
    char* sl = smem + (i & 1) * SLOT;
    const int it = its[i];
    const bool en = it < 640;
    const int E = en ? 11 : 9;
    const float* feats = en ? en_feats + (long)it*1760 : al_feats + (long)(it-640)*1440;
    const unsigned short* Wg = ws + (en ? OFF_WEN : OFF_WAL);
    const unsigned short* Bg = ws + (en ? OFF_BGEN : OFF_BGAL);
    const float* bin  = en ? en_bin  : al_bin;
    const float* bres = en ? en_bres : al_bres;
    float* emb = en ? emb_en + (long)it*1024 : emb_al + (long)(it-640)*1024;

    stackP(sl, E, Wg, bin, bres);
    __syncthreads();   // h complete (P-build reads cross-wave rows)

    // ---- P-build: thread = (agent a, k-quad kq)
    const int a = t >> 4, kq = t & 15, k0 = kq * 4;
    float acc[4][10];
#pragma unroll
    for (int kk = 0; kk < 4; kk++)
#pragma unroll
      for (int f = 0; f < 10; f++) acc[kk][f] = 0.f;
    for (int e = 0; e < E; e++) {
      int row = a * E + e;
      s16x8 xv8 = *(const s16x8*)(sl + xoffc(row, 0));
      unsigned xv2 = *(const unsigned*)(sl + xoffc(row, 16));
      float xf[10];
#pragma unroll
      for (int f = 0; f < 8; f++) xf[f] = b2f((unsigned short)xv8[f]);
      xf[8] = b2f((unsigned short)(xv2 & 0xFFFF));
      xf[9] = b2f((unsigned short)(xv2 >> 16));
      u32x2 hp = *(const u32x2*)(sl + hoffc(row, k0*2));
      float hf[4] = { b2f((unsigned short)(hp.x & 0xFFFF)), b2f((unsigned short)(hp.x >> 16)),
                      b2f((unsigned short)(hp.y & 0xFFFF)), b2f((unsigned short)(hp.y >> 16)) };
#pragma unroll
      for (int kk = 0; kk < 4; kk++)
#pragma unroll
        for (int f = 0; f < 10; f++) acc[kk][f] += hf[kk] * xf[f];
    }
    float sxv = 0.f; int a2 = 0, fx = 0;
    if (t < 160) {
      a2 = t / 10; fx = t - a2 * 10;
      for (int e = 0; e < E; e++) sxv += feats[(a2*E + e)*10 + fx];
    }
    __syncthreads();   // all x/h reads done; P overlays slot front

    unsigned short* P2 = (unsigned short*)sl;
    {
      unsigned* Pw = (unsigned*)(P2 + a*PSTR + k0*10);   // 40 bf16 = 20 u32
#pragma unroll
      for (int m = 0; m < 20; m++) {
        const int v0 = 2*m, v1 = 2*m + 1;
        Pw[m] = cvtpk(acc[v0/10][v0%10], acc[v1/10][v1%10]);
      }
    }
    if (t < 160) P2[a2*PSTR + 640 + fx] = f2b(sxv);
    if (t < 352) { int a3 = t / 22, c = t - a3*22; P2[a3*PSTR + 650 + c] = 0; }
    if (i + 1 < nit) {   // prefetch next item's x into the other slot
      int itn = its[i+1];
      const float* fn = (itn < 640) ? en_feats + (long)itn*1760
                                    : al_feats + (long)(itn-640)*1440;
      stage_item(fn, (itn < 640) ? 176 : 144, smem + ((i+1) & 1) * SLOT);
    }
    __syncthreads();   // P ready + staged x visible

    // ---- GEMM: wave wv owns n-tile wv; M = 16 agents; B direct from global
    f32x4 g0 = {0.f,0.f,0.f,0.f}, g1 = {0.f,0.f,0.f,0.f};
    const unsigned short* Bw = Bg + (wv*16 + lrow)*32 + lk8;
#pragma unroll
    for (int c = 0; c < 21; c++) {
      s16x8 af = *(const s16x8*)&P2[lrow*PSTR + c*32 + lk8];
      s16x8 bf = ldg8(Bw + c*2048);
      if (c & 1) g1 = MFMA(af, bf, g1); else g0 = MFMA(af, bf, g0);
    }
#pragma unroll
    for (int r = 0; r < 4; r++)
      emb[(gq*4 + r)*64 + wv*16 + lrow] = g0[r] + g1[r];
  }
}

// ================= kfused (R5 verbatim) =================
__global__ __launch_bounds__(256) void kfused(
    const float* __restrict__ own, const float* __restrict__ agent_emb,
    const float* __restrict__ action_emb,
    const int* __restrict__ agent_idx, const int* __restrict__ last_action,
    const float* __restrict__ emb_en, const float* __restrict__ emb_al,
    const float* __restrict__ hidden,
    const unsigned short* __restrict__ ws,
    const float* __restrict__ fc1_b, const float* __restrict__ bi,
    const float* __restrict__ bh, const float* __restrict__ fc2_b,
    float* __restrict__ qout, float* __restrict__ hhout,
    unsigned short* __restrict__ g_bf, float* __restrict__ hb)
{
  __shared__ unsigned short own_lds[16*32];
  __shared__ unsigned short x_lds[16*HSTR];
  __shared__ unsigned short hp_lds[16*HSTR];
  __shared__ unsigned short hh_lds[16*HSTR];
  const int t = threadIdx.x;
  const int l = t & 63, wv = t >> 6;
  const int lrow = l & 15, lk8 = (l >> 4) * 8, lr4 = (l >> 4) * 4;
  const int n0 = blockIdx.x * 16;

  const unsigned short* fc1T = ws + OFF_FC1T;
  const unsigned short* wiT  = ws + OFF_WIT;
  const unsigned short* whT  = ws + OFF_WHT;
  const unsigned short* howT = ws + OFF_HOWT;
  const unsigned short* fc2e = ws + OFF_FC2E;

  for (int i = t; i < 512; i += 256) own_lds[i] = f2b(own[n0*32 + i]);
  for (int i = t; i < 1024; i += 256) hp_lds[(i >> 6)*HSTR + (i & 63)] = f2b(hidden[n0*64 + i]);
  __syncthreads();

  const int j = wv * 16 + lrow;
  {
    s16x8 a0 = *(const s16x8*)&own_lds[lrow*32 + lk8];
    s16x8 b0 = ldg8(fc1T + (wv*16 + lrow)*32 + lk8);
    f32x4 c0 = MFMA(a0, b0, f32x4{0.f,0.f,0.f,0.f});
    float fb = fc1_b[j];
#pragma unroll
    for (int r = 0; r < 4; r++) {
      int aa = lr4 + r; int n = n0 + aa;
      int ai = agent_idx[n], la = last_action[n];
      float v = c0[r] + fb + agent_emb[ai*64 + j] + action_emb[la*64 + j]
              + emb_en[(long)n*64 + j] + emb_al[(long)n*64 + j];
      x_lds[aa*HSTR + j] = f2b(fmaxf(v, 0.f));
    }
  }
  __syncthreads();

  {
    s16x8 xa[2], ha[2];
#pragma unroll
    for (int s = 0; s < 2; s++) {
      xa[s] = *(const s16x8*)&x_lds[lrow*HSTR + s*32 + lk8];
      ha[s] = *(const s16x8*)&hp_lds[lrow*HSTR + s*32 + lk8];
    }
    f32x4 gi[3], gh[3];
#pragma unroll
    for (int g3 = 0; g3 < 3; g3++) { gi[g3] = f32x4{0.f,0.f,0.f,0.f}; gh[g3] = f32x4{0.f,0.f,0.f,0.f}; }
#pragma unroll
    for (int g3 = 0; g3 < 3; g3++) {
      int tl = wv + g3 * 4;
#pragma unroll
      for (int s = 0; s < 2; s++) {
        gi[g3] = MFMA(xa[s], ldg8(wiT + (tl*16 + lrow)*64 + s*32 + lk8), gi[g3]);
        gh[g3] = MFMA(ha[s], ldg8(whT + (tl*16 + lrow)*64 + s*32 + lk8), gh[g3]);
      }
    }
    float bir = bi[j], biz = bi[64 + j], bin_ = bi[128 + j];
    float bhr = bh[j], bhz = bh[64 + j], bhn = bh[128 + j];
#pragma unroll
    for (int r = 0; r < 4; r++) {
      int aa = lr4 + r; int n = n0 + aa;
      float rr = 1.f / (1.f + __expf(-(gi[0][r] + bir + gh[0][r] + bhr)));
      float zz = 1.f / (1.f + __expf(-(gi[1][r] + biz + gh[1][r] + bhz)));
      float nn = tanhf(gi[2][r] + bin_ + rr * (gh[2][r] + bhn));
      float hp = hidden[n*64 + j];
      float hhv = (1.f - zz) * nn + zz * hp;
      hhout[n*64 + j] = hhv;
      hh_lds[aa*HSTR + j] = f2b(hhv);
    }
  }
  __syncthreads();

  {
    s16x8 hha[2];
#pragma unroll
    for (int s = 0; s < 2; s++) hha[s] = *(const s16x8*)&hh_lds[lrow*HSTR + s*32 + lk8];
    f32x4 gc = {0.f,0.f,0.f,0.f};
#pragma unroll
    for (int s = 0; s < 2; s++) gc = MFMA(hha[s], ldg8(howT + (wv*16 + lrow)*64 + s*32 + lk8), gc);
#pragma unroll
    for (int r = 0; r < 4; r++) g_bf[(n0 + lr4 + r)*64 + wv*16 + lrow] = f2b(gc[r]);
    if (wv == 0) {
      f32x4 qc = {0.f,0.f,0.f,0.f};
#pragma unroll
      for (int s = 0; s < 2; s++) qc = MFMA(hha[s], ldg8(fc2e + lrow*64 + s*32 + lk8), qc);
#pragma unroll
      for (int r = 0; r < 4; r++) {
        int n = n0 + lr4 + r;
        if (lrow < 6)       qout[n*17 + lrow] = qc[r] + fc2_b[lrow];
        else if (lrow == 6) hb[n] = qc[r];
      }
    }
  }
}

// ================= stack_batch for kattack (R5 verbatim) =================
template<int TMAX, bool WLAST>
DI void stack_batch(const unsigned short* __restrict__ x_lds,
                    unsigned short* const (&hbp)[TMAX], const int (&tis)[TMAX], int NT,
                    const unsigned short* __restrict__ wg,
                    const float* __restrict__ bin, const float* __restrict__ bres,
                    f32x4 (&hval)[TMAX][4])
{
  const int l = threadIdx.x & 63;
  const int lrow = l & 15, gq = l >> 4, lk8 = gq * 8;
  {
    s16x8 wf[4]; f32x4 bv[4];
#pragma unroll
    for (int mt = 0; mt < 4; mt++) {
      wf[mt] = ldg8(wg + (mt*16 + lrow)*32 + lk8);
      bv[mt] = *(const f32x4*)(bin + mt*16 + gq*4);
    }
#pragma unroll
    for (int tt = 0; tt < TMAX; tt++) {
      if (tis[tt] < NT) {
        s16x8 xf = *(const s16x8*)&x_lds[(tis[tt]*16 + lrow)*XSTR + lk8];
#pragma unroll
        for (int mt = 0; mt < 4; mt++) {
          f32x4 d = MFMA(wf[mt], xf, bv[mt]);
#pragma unroll
          for (int r = 0; r < 4; r++) hval[tt][mt][r] = fmaxf(d[r], 0.f);
        }
        unsigned short* wr = hbp[tt] + lrow*HSTR;
#pragma unroll
        for (int mt = 0; mt < 4; mt++) {
          u32x2 pw;
          pw.x = cvtpk(hval[tt][mt][0], hval[tt][mt][1]);
          pw.y = cvtpk(hval[tt][mt][2], hval[tt][mt][3]);
          *(u32x2*)&wr[mt*16 + gq*4] = pw;
        }
      }
    }
  }
#pragma unroll
  for (int d = 0; d < 2; d++) {
    const unsigned short* wt = wg + 2048 + d * 4096;
    s16x8 wf[4][2]; f32x4 bv[4];
#pragma unroll
    for (int mt = 0; mt < 4; mt++) {
      wf[mt][0] = ldg8(wt + (mt*16 + lrow)*64 + lk8);
      wf[mt][1] = ldg8(wt + (mt*16 + lrow)*64 + 32 + lk8);
      bv[mt] = *(const f32x4*)(bres + d*64 + mt*16 + gq*4);
    }
#pragma unroll
    for (int tt = 0; tt < TMAX; tt++) {
      if (tis[tt] < NT) {
        const unsigned short* hr = hbp[tt] + lrow*HSTR;
        s16x8 b0 = *(const s16x8*)&hr[lk8];
        s16x8 b1 = *(const s16x8*)&hr[32 + lk8];
#pragma unroll
        for (int mt = 0; mt < 4; mt++) {
          f32x4 a = MFMA(wf[mt][0], b0, bv[mt]);
          a = MFMA(wf[mt][1], b1, a);
#pragma unroll
          for (int r = 0; r < 4; r++)
            hval[tt][mt][r] = fmaxf(a[r], 0.f) + hval[tt][mt][r];
        }
        if (d == 0 || WLAST) {
          unsigned short* wr = hbp[tt] + lrow*HSTR;
#pragma unroll
          for (int mt = 0; mt < 4; mt++) {
            u32x2 pw;
            pw.x = cvtpk(hval[tt][mt][0], hval[tt][mt][1]);
            pw.y = cvtpk(hval[tt][mt][2], hval[tt][mt][3]);
            *(u32x2*)&wr[mt*16 + gq*4] = pw;
          }
        }
      }
    }
  }
}

// ================= kattack (R5 verbatim) =================
__global__ __launch_bounds__(256) void kattack(
    const float* __restrict__ en_feats, const unsigned short* __restrict__ ws,
    const float* __restrict__ how_bin, const float* __restrict__ how_bres,
    const float* __restrict__ hob_bin, const float* __restrict__ hob_bres,
    const unsigned short* __restrict__ g_bf, const float* __restrict__ hbuf,
    const float* __restrict__ hob_wout, const float* __restrict__ hob_bout,
    float* __restrict__ qout)
{
  __shared__ __align__(16) char smem[41728];
  unsigned short* x_lds = (unsigned short*)smem;
  unsigned short* scr   = (unsigned short*)(smem + 14080);
  const int t = threadIdx.x;
  const int l = t & 63, wv = t >> 6;
  const int lrow = l & 15, gq = l >> 4;
  const int blk = blockIdx.x;
  const float* feats = en_feats + (long)blk * 1760;

  for (int idx = t; idx < 176*32; idx += 256) {
    int row = idx >> 5, c = idx & 31;
    x_lds[row*XSTR + c] = (c < 10) ? f2b(feats[row*10 + c]) : (unsigned short)0;
  }
  __syncthreads();

  int tis[3] = {wv, wv + 4, wv + 8};
  unsigned short* hbp[3] = { scr + (wv*3+0)*16*HSTR, scr + (wv*3+1)*16*HSTR, scr + (wv*3+2)*16*HSTR };
  f32x4 hval[3][4];

  stack_batch<3, false>(x_lds, hbp, tis, 11, ws + OFF_WHOB, hob_bin, hob_bres, hval);
  f32x4 hw[4];
#pragma unroll
  for (int mt = 0; mt < 4; mt++) hw[mt] = *(const f32x4*)(hob_wout + mt*16 + gq*4);
  float qbv[3] = {0.f, 0.f, 0.f};
#pragma unroll
  for (int tt = 0; tt < 3; tt++) {
    if (tis[tt] < 11) {
      float s = 0.f;
#pragma unroll
      for (int mt = 0; mt < 4; mt++)
#pragma unroll
        for (int r = 0; r < 4; r++) s += hval[tt][mt][r] * hw[mt][r];
      s += __shfl_xor(s, 16, 64);
      s += __shfl_xor(s, 32, 64);
      qbv[tt] = s;
    }
  }

  stack_batch<3, false>(x_lds, hbp, tis, 11, ws + OFF_WHOW, how_bin, how_bres, hval);
  const float hob_b0 = hob_bout[0];
#pragma unroll
  for (int tt = 0; tt < 3; tt++) {
    if (tis[tt] < 11) {
      int row = tis[tt]*16 + lrow;
      unsigned ag = (unsigned)row / 11u;
      int n = blk*16 + (int)ag;
      float s = 0.f;
#pragma unroll
      for (int mt = 0; mt < 4; mt++) {
        u32x2 gv = *(const u32x2*)(g_bf + (long)n*64 + mt*16 + gq*4);
        s += hval[tt][mt][0] * b2f((unsigned short)(gv.x & 0xFFFF))
           + hval[tt][mt][1] * b2f((unsigned short)(gv.x >> 16))
           + hval[tt][mt][2] * b2f((unsigned short)(gv.y & 0xFFFF))
           + hval[tt][mt][3] * b2f((unsigned short)(gv.y >> 16));
      }
      s += __shfl_xor(s, 16, 64);
      s += __shfl_xor(s, 32, 64);
      if (l < 16) {
        int e = row - (int)ag * 11;
        qout[n*17 + 6 + e] = s + qbv[tt] + hbuf[n] + hob_b0;
      }
    }
  }
}

extern "C" void kernel_launch(void* const* d_in, const int* in_sizes, int n_in,
                              void* d_out, int out_size, void* d_ws, size_t ws_size,
                              hipStream_t stream)
{
  (void)in_sizes; (void)n_in; (void)out_size; (void)ws_size;
  const float* own        = (const float*)d_in[0];
  const float* enemy      = (const float*)d_in[1];
  const float* ally       = (const float*)d_in[2];
  const float* hidden     = (const float*)d_in[3];
  const float* fc1_w      = (const float*)d_in[4];
  const float* fc1_b      = (const float*)d_in[5];
  const float* agent_emb  = (const float*)d_in[6];
  const float* action_emb = (const float*)d_in[7];
  const float* hen_win  = (const float*)d_in[8];  const float* hen_bin  = (const float*)d_in[9];
  const float* hen_wres = (const float*)d_in[10]; const float* hen_bres = (const float*)d_in[11];
  const float* hen_wout = (const float*)d_in[12]; const float* hen_bout = (const float*)d_in[13];
  const float* hal_win  = (const float*)d_in[14]; const float* hal_bin  = (const float*)d_in[15];
  const float* hal_wres = (const float*)d_in[16]; const float* hal_bres = (const float*)d_in[17];
  const float* hal_wout = (const float*)d_in[18]; const float* hal_bout = (const float*)d_in[19];
  const float* gru_wi = (const float*)d_in[20];   const float* gru_wh = (const float*)d_in[21];
  const float* gru_bi = (const float*)d_in[22];   const float* gru_bh = (const float*)d_in[23];
  const float* fc2_w  = (const float*)d_in[24];   const float* fc2_b  = (const float*)d_in[25];
  const float* how_win  = (const float*)d_in[26]; const float* how_bin  = (const float*)d_in[27];
  const float* how_wres = (const float*)d_in[28]; const float* how_bres = (const float*)d_in[29];
  const float* how_wout = (const float*)d_in[30]; const float* how_bout = (const float*)d_in[31];
  const float* hob_win  = (const float*)d_in[32]; const float* hob_bin  = (const float*)d_in[33];
  const float* hob_wres = (const float*)d_in[34]; const float* hob_bres = (const float*)d_in[35];
  const float* hob_wout = (const float*)d_in[36]; const float* hob_bout = (const float*)d_in[37];
  const int* agent_idx   = (const int*)d_in[38];
  const int* last_action = (const int*)d_in[39];

  unsigned short* ws = (unsigned short*)d_ws;
  float* emb_en = (float*)((char*)d_ws + B_EMB_EN);
  float* emb_al = (float*)((char*)d_ws + B_EMB_AL);
  float* hb     = (float*)((char*)d_ws + B_HB);
  unsigned short* g_bf = (unsigned short*)((char*)d_ws + B_GBF);

  float* q  = (float*)d_out;
  float* hh = q + 1024*10*17;

  kprep<<<128, 256, 0, stream>>>(hen_win, hen_wres, hal_win, hal_wres,
      how_win, how_wres, hob_win, hob_wres,
      hen_wout, hen_bout, hal_wout, hal_bout,
      gru_wi, gru_wh, fc1_w, fc2_w, how_bout, how_wout, ws);
  khyp_ea<<<512, 256, 0, stream>>>(enemy, ally, ws,
      hen_bin, hen_bres, hal_bin, hal_bres, emb_en, emb_al);
  kfused<<<640, 256, 0, stream>>>(own, agent_emb, action_emb, agent_idx, last_action,
      emb_en, emb_al, hidden, ws, fc1_b, gru_bi, gru_bh, fc2_b, q, hh, g_bf, hb);
  kattack<<<640, 256, 0, stream>>>(enemy, ws, how_bin, how_bres, hob_bin, hob_bres,
      g_bf, hb, hob_wout, hob_bout, q);
}